// Round 4
// baseline (836.749 us; speedup 1.0000x reference)
//
#include <hip/hip_runtime.h>
#include <math.h>

#define Q_LEN 512
#define M_LEN 512
#define KL    1024
#define BSZ   4
#define DM    1024
#define NH    16
#define DHD   64
#define NG    4
#define DGRP  256
#define RL    1024
#define LN_EPS 1e-6f
#define ATT_SCALE 0.125f

__device__ __forceinline__ float wave_sum64(float v) {
#pragma unroll
    for (int off = 32; off > 0; off >>= 1) v += __shfl_xor(v, off);
    return v;
}

// ---------------- group LayerNorm for w (G=4 groups of 256) ----------------
__global__ __launch_bounds__(64) void group_ln_kernel(
    const float* __restrict__ w, const float* __restrict__ gamma,
    const float* __restrict__ beta, float* __restrict__ out)
{
    int bid = blockIdx.x;              // (q*BSZ + b)*NG + g
    int g = bid & (NG - 1);
    long long row = bid >> 2;
    int t = threadIdx.x;
    long long base = row * DM + g * DGRP + t * 4;
    float4 x = *(const float4*)(w + base);
    float mean = wave_sum64(x.x + x.y + x.z + x.w) * (1.0f / 256.0f);
    float dx = x.x - mean, dy = x.y - mean, dz = x.z - mean, dw = x.w - mean;
    float ss = wave_sum64(dx * dx + dy * dy + dz * dz + dw * dw);
    float inv = 1.0f / (sqrtf(ss * (1.0f / 255.0f)) + LN_EPS);   // ddof=1, (x-m)/(std+eps)
    int db = g * DGRP + t * 4;
    float4 ga = *(const float4*)(gamma + db);
    float4 be = *(const float4*)(beta + db);
    float4 o;
    o.x = ga.x * (dx * inv) + be.x;
    o.y = ga.y * (dy * inv) + be.y;
    o.z = ga.z * (dz * inv) + be.z;
    o.w = ga.w * (dw * inv) + be.w;
    *(float4*)(out + base) = o;
}

// ---------------- full LayerNorm for kv = concat(mems, w) ----------------
__global__ __launch_bounds__(256) void kv_ln_kernel(
    const float* __restrict__ mems, const float* __restrict__ w,
    const float* __restrict__ gamma, const float* __restrict__ beta,
    float* __restrict__ out)
{
    int row = blockIdx.x;              // k*BSZ + b
    int k = row >> 2, b = row & 3;
    const float* src = (k < M_LEN) ? (mems + ((long long)k * BSZ + b) * DM)
                                   : (w + ((long long)(k - M_LEN) * BSZ + b) * DM);
    int t = threadIdx.x;
    float4 x = *(const float4*)(src + t * 4);
    __shared__ float red[4];
    float s = wave_sum64(x.x + x.y + x.z + x.w);
    int wv = t >> 6, ln = t & 63;
    if (ln == 0) red[wv] = s;
    __syncthreads();
    float mean = (red[0] + red[1] + red[2] + red[3]) * (1.0f / 1024.0f);
    float dx = x.x - mean, dy = x.y - mean, dz = x.z - mean, dw = x.w - mean;
    float ss = wave_sum64(dx * dx + dy * dy + dz * dz + dw * dw);
    __syncthreads();
    if (ln == 0) red[wv] = ss;
    __syncthreads();
    float var = (red[0] + red[1] + red[2] + red[3]) * (1.0f / 1023.0f);
    float inv = 1.0f / (sqrtf(var) + LN_EPS);
    int db = t * 4;
    float4 ga = *(const float4*)(gamma + db);
    float4 be = *(const float4*)(beta + db);
    float4 o;
    o.x = ga.x * (dx * inv) + be.x;
    o.y = ga.y * (dy * inv) + be.y;
    o.z = ga.z * (dz * inv) + be.z;
    o.w = ga.w * (dw * inv) + be.w;
    *(float4*)(out + (long long)row * DM + db) = o;
}

// --------- generic f32 GEMM  C[M,N] = A[M,K] * W[N,K]^T (+add1 +add2) ------
// z-dim strides allow grouped (per-g) launches in one kernel.
__global__ __launch_bounds__(256) void gemm_nt_kernel(
    const float* __restrict__ A, long long aZ, int lda,
    const float* __restrict__ W, long long wZ, int ldw,
    float* __restrict__ C, long long cZ, int ldc,
    int M, int N, int K,
    const float* __restrict__ add1, long long a1Z, int lda1,
    const float* __restrict__ add2, long long a2Z, int lda2)
{
    int z = blockIdx.z;
    A += (long long)z * aZ;
    W += (long long)z * wZ;
    C += (long long)z * cZ;
    if (add1) add1 += (long long)z * a1Z;
    if (add2) add2 += (long long)z * a2Z;
    int m0 = blockIdx.y * 64, n0 = blockIdx.x * 64;
    int t = threadIdx.x;
    int tr = t >> 4, tc = t & 15;
    int lr = t >> 2, lc = (t & 3) * 4;
    __shared__ float As[16][68];
    __shared__ float Ws[16][68];
    float acc[4][4] = {};
    for (int k0 = 0; k0 < K; k0 += 16) {
        float4 av = *(const float4*)(A + (long long)(m0 + lr) * lda + k0 + lc);
        float4 wv = *(const float4*)(W + (long long)(n0 + lr) * ldw + k0 + lc);
        As[lc + 0][lr] = av.x; As[lc + 1][lr] = av.y;
        As[lc + 2][lr] = av.z; As[lc + 3][lr] = av.w;
        Ws[lc + 0][lr] = wv.x; Ws[lc + 1][lr] = wv.y;
        Ws[lc + 2][lr] = wv.z; Ws[lc + 3][lr] = wv.w;
        __syncthreads();
#pragma unroll
        for (int k = 0; k < 16; ++k) {
            float a_[4], b_[4];
            *(float4*)a_ = *(const float4*)&As[k][tr * 4];
            *(float4*)b_ = *(const float4*)&Ws[k][tc * 4];
#pragma unroll
            for (int ii = 0; ii < 4; ++ii)
#pragma unroll
                for (int jj = 0; jj < 4; ++jj)
                    acc[ii][jj] += a_[ii] * b_[jj];
        }
        __syncthreads();
    }
#pragma unroll
    for (int ii = 0; ii < 4; ++ii) {
        long long row = m0 + tr * 4 + ii;
#pragma unroll
        for (int jj = 0; jj < 4; ++jj) {
            int col = n0 + tc * 4 + jj;
            float v = acc[ii][jj];
            if (add1) v += add1[row * lda1 + col];
            if (add2) v += add2[row * lda2 + col];
            C[row * ldc + col] = v;
        }
    }
}

// --------- corr[n,k] = sum_d (rrb[n,d]-rwb[n,d]) * r_head_k[k,n,d] ---------
__global__ __launch_bounds__(256) void corr_kernel(
    const float* __restrict__ r_hk, const float* __restrict__ rwb,
    const float* __restrict__ rrb, float* __restrict__ corr)
{
    int n = blockIdx.y;
    int k = blockIdx.x * 4 + (threadIdx.x >> 6);
    int d = threadIdx.x & 63;
    float diff = rrb[n * DHD + d] - rwb[n * DHD + d];
    float v = diff * r_hk[(long long)k * DM + n * DHD + d];
    v = wave_sum64(v);
    if (d == 0) corr[n * RL + k] = v;
}

// ---------------- flash-style rel-shift attention ----------------
// grid: (Q_LEN/64, BSZ*NH). One block = 64 q-rows for one (b, n).
// S[i,j] = (qrw[i]·k[j] + qrw[i]·rk[j+511-i] + corr[j+511-i]) * SCALE, mask j>i+512.
__global__ __launch_bounds__(256) void attn_kernel(
    const float* __restrict__ head_q, const float* __restrict__ head_k,
    const float* __restrict__ head_v, const float* __restrict__ r_hk,
    const float* __restrict__ corr, const float* __restrict__ rwb,
    float* __restrict__ attn_out)
{
    __shared__ float QsT[64][68];     // [d][i]  (q + r_w_bias)
    __shared__ float KsT[64][68];     // [d][j]
    __shared__ float Vs[64][68];      // [j][d]
    __shared__ float Ps[64][68];      // [i][j]
    __shared__ float RKsT[64][132];   // [d][kk], kk in [0,128)
    __shared__ float BDs[64][128];    // [i][kk]
    __shared__ float corrS[128];

    int bh = blockIdx.y;
    int b = bh >> 4, n = bh & 15;
    int i0 = blockIdx.x * 64;
    int t = threadIdx.x;
    int tr = t >> 4, tc = t & 15;
    int lr = t >> 2, lc = (t & 3) * 4;

    {   // stage Q tile once, adding r_w_bias
        const float* qsrc = head_q + ((long long)(i0 + lr) * BSZ + b) * DM + n * DHD;
#pragma unroll
        for (int rr = 0; rr < 4; ++rr) {
            int c = lc + 16 * rr;
            float4 v = *(const float4*)(qsrc + c);
            float4 bi = *(const float4*)(rwb + n * DHD + c);
            QsT[c + 0][lr] = v.x + bi.x;
            QsT[c + 1][lr] = v.y + bi.y;
            QsT[c + 2][lr] = v.z + bi.z;
            QsT[c + 3][lr] = v.w + bi.w;
        }
    }

    float m_[4], l_[4], O_[4][4];
#pragma unroll
    for (int ii = 0; ii < 4; ++ii) {
        m_[ii] = -INFINITY; l_[ii] = 0.0f;
#pragma unroll
        for (int jj = 0; jj < 4; ++jj) O_[ii][jj] = 0.0f;
    }

    int nJ = ((i0 + 575) >> 6) + 1;
    if (nJ > 16) nJ = 16;

    for (int jt = 0; jt < nJ; ++jt) {
        int j0 = jt * 64;
        int ka = j0 + 448 - i0;     // rk window base; consumed kidx = ka + 63 + (jj_g - ii_g)
        {
            const float* ksrc = head_k + ((long long)(j0 + lr) * BSZ + b) * DM + n * DHD;
            const float* vsrc = head_v + ((long long)(j0 + lr) * BSZ + b) * DM + n * DHD;
#pragma unroll
            for (int rr = 0; rr < 4; ++rr) {
                int c = lc + 16 * rr;
                float4 kv4 = *(const float4*)(ksrc + c);
                KsT[c + 0][lr] = kv4.x;
                KsT[c + 1][lr] = kv4.y;
                KsT[c + 2][lr] = kv4.z;
                KsT[c + 3][lr] = kv4.w;
                *(float4*)&Vs[lr][c] = *(const float4*)(vsrc + c);
            }
#pragma unroll
            for (int half = 0; half < 2; ++half) {
                int rrow = lr + half * 64;
                int kidx = ka + rrow;
                bool ok = (kidx >= 0) && (kidx < RL);
                const float* rsrc = r_hk + (long long)kidx * DM + n * DHD;
#pragma unroll
                for (int rr = 0; rr < 4; ++rr) {
                    int c = lc + 16 * rr;
                    float4 v4 = ok ? *(const float4*)(rsrc + c) : make_float4(0.f, 0.f, 0.f, 0.f);
                    RKsT[c + 0][rrow] = v4.x;
                    RKsT[c + 1][rrow] = v4.y;
                    RKsT[c + 2][rrow] = v4.z;
                    RKsT[c + 3][rrow] = v4.w;
                }
            }
            if (t < 128) {
                int kidx = ka + t;
                corrS[t] = (kidx >= 0 && kidx < RL) ? corr[n * RL + kidx] : 0.0f;
            }
        }
        __syncthreads();

        // three register-tiled GEMMs over d: AC(64x64), BD halves (64x128)
        float ac[4][4] = {};
        float bd0[4][4] = {};
        float bd1[4][4] = {};
        for (int d = 0; d < DHD; ++d) {
            float q4[4], k4[4], ra[4], rb[4];
            *(float4*)q4 = *(const float4*)&QsT[d][tr * 4];
            *(float4*)k4 = *(const float4*)&KsT[d][tc * 4];
            *(float4*)ra = *(const float4*)&RKsT[d][tc * 4];
            *(float4*)rb = *(const float4*)&RKsT[d][64 + tc * 4];
#pragma unroll
            for (int ii = 0; ii < 4; ++ii)
#pragma unroll
                for (int jj = 0; jj < 4; ++jj) {
                    ac[ii][jj] += q4[ii] * k4[jj];
                    bd0[ii][jj] += q4[ii] * ra[jj];
                    bd1[ii][jj] += q4[ii] * rb[jj];
                }
        }
#pragma unroll
        for (int ii = 0; ii < 4; ++ii)
#pragma unroll
            for (int jj = 0; jj < 4; ++jj) {
                BDs[tr * 4 + ii][tc * 4 + jj] = bd0[ii][jj] + corrS[tc * 4 + jj];
                BDs[tr * 4 + ii][64 + tc * 4 + jj] = bd1[ii][jj] + corrS[64 + tc * 4 + jj];
            }
        __syncthreads();

        // assemble S (rel-shift diagonal read), mask, online softmax
#pragma unroll
        for (int ii = 0; ii < 4; ++ii) {
            int i = i0 + tr * 4 + ii;
            float pv[4];
            float rowm = -INFINITY;
#pragma unroll
            for (int jj = 0; jj < 4; ++jj) {
                int j = j0 + tc * 4 + jj;
                float s = -INFINITY;
                if (j <= i + M_LEN) {
                    int kk = 63 + (tc * 4 + jj) - (tr * 4 + ii);
                    s = (ac[ii][jj] + BDs[tr * 4 + ii][kk]) * ATT_SCALE;
                }
                pv[jj] = s;
                rowm = fmaxf(rowm, s);
            }
            rowm = fmaxf(rowm, __shfl_xor(rowm, 1));
            rowm = fmaxf(rowm, __shfl_xor(rowm, 2));
            rowm = fmaxf(rowm, __shfl_xor(rowm, 4));
            rowm = fmaxf(rowm, __shfl_xor(rowm, 8));
            float newm = fmaxf(m_[ii], rowm);
            float alpha = __expf(m_[ii] - newm);
            float rs = 0.0f;
#pragma unroll
            for (int jj = 0; jj < 4; ++jj) {
                float p = __expf(pv[jj] - newm);
                rs += p;
                Ps[tr * 4 + ii][tc * 4 + jj] = p;
            }
            rs += __shfl_xor(rs, 1);
            rs += __shfl_xor(rs, 2);
            rs += __shfl_xor(rs, 4);
            rs += __shfl_xor(rs, 8);
            l_[ii] = l_[ii] * alpha + rs;
            m_[ii] = newm;
#pragma unroll
            for (int jj = 0; jj < 4; ++jj) O_[ii][jj] *= alpha;
        }
        __syncthreads();

        // PV: O[i][d] += sum_j P[i,j] * V[j,d]
        for (int j = 0; j < 64; ++j) {
            float v4[4];
            *(float4*)v4 = *(const float4*)&Vs[j][tc * 4];
#pragma unroll
            for (int ii = 0; ii < 4; ++ii) {
                float p = Ps[tr * 4 + ii][j];
#pragma unroll
                for (int jj = 0; jj < 4; ++jj) O_[ii][jj] += p * v4[jj];
            }
        }
        __syncthreads();
    }

#pragma unroll
    for (int ii = 0; ii < 4; ++ii) {
        long long i = i0 + tr * 4 + ii;
        float invl = 1.0f / l_[ii];
#pragma unroll
        for (int jj = 0; jj < 4; ++jj)
            attn_out[(i * BSZ + b) * DM + n * DHD + tc * 4 + jj] = O_[ii][jj] * invl;
    }
}

extern "C" void kernel_launch(void* const* d_in, const int* in_sizes, int n_in,
                              void* d_out, int out_size, void* d_ws, size_t ws_size,
                              hipStream_t stream) {
    const float* w       = (const float*)d_in[0];
    const float* r       = (const float*)d_in[1];
    const float* rwb     = (const float*)d_in[2];
    const float* rrb     = (const float*)d_in[3];
    const float* mems    = (const float*)d_in[4];
    const float* gamma_q = (const float*)d_in[5];
    const float* beta_q  = (const float*)d_in[6];
    const float* gamma_kv= (const float*)d_in[7];
    const float* beta_kv = (const float*)d_in[8];
    const float* Wq      = (const float*)d_in[9];
    const float* Wiq     = (const float*)d_in[10];
    const float* Wk      = (const float*)d_in[11];
    const float* Wv      = (const float*)d_in[12];
    const float* Wr      = (const float*)d_in[13];
    const float* Wintra  = (const float*)d_in[14];
    const float* Winter  = (const float*)d_in[15];
    float* out = (float*)d_out;
    float* ws = (float*)d_ws;

    float* w_norm  = ws;                      // 2,097,152
    float* kv_norm = w_norm + 2097152;        // 4,194,304
    float* head_q  = kv_norm + 4194304;       // 2,097,152
    float* head_k  = head_q + 2097152;        // 4,194,304
    float* head_v  = head_k + 4194304;        // 4,194,304
    float* r_hk    = head_v + 4194304;        // 1,048,576
    float* corr    = r_hk + 1048576;          // 16,384
    float* attn_o  = corr + 16384;            // 2,097,152
    float* tmp     = attn_o + 2097152;        // 524,288 (qg, then inter)

    group_ln_kernel<<<dim3(Q_LEN * BSZ * NG), 64, 0, stream>>>(w, gamma_q, beta_q, w_norm);
    kv_ln_kernel<<<dim3(KL * BSZ), 256, 0, stream>>>(mems, w, gamma_kv, beta_kv, kv_norm);

    // head_k = kv_norm * Wk^T   [4096,1024]
    gemm_nt_kernel<<<dim3(16, 64, 1), 256, 0, stream>>>(
        kv_norm, 0, DM, Wk, 0, DM, head_k, 0, DM, KL * BSZ, DM, DM,
        nullptr, 0, 0, nullptr, 0, 0);
    // head_v = kv_norm * Wv^T
    gemm_nt_kernel<<<dim3(16, 64, 1), 256, 0, stream>>>(
        kv_norm, 0, DM, Wv, 0, DM, head_v, 0, DM, KL * BSZ, DM, DM,
        nullptr, 0, 0, nullptr, 0, 0);
    // q_global -> tmp  [2048,256]
    gemm_nt_kernel<<<dim3(4, 32, 1), 256, 0, stream>>>(
        w_norm, 0, DM, Wiq, 0, DM, tmp, 0, DGRP, Q_LEN * BSZ, DGRP, DM,
        nullptr, 0, 0, nullptr, 0, 0);
    // head_q = grouped(w_norm * Wq^T) + q_global  (z = group)
    gemm_nt_kernel<<<dim3(4, 32, 4), 256, 0, stream>>>(
        w_norm, DGRP, DM, Wq, DGRP * DGRP, DGRP, head_q, DGRP, DM,
        Q_LEN * BSZ, DGRP, DGRP, tmp, 0, DGRP, nullptr, 0, 0);
    // r_head_k = grouped(r * Wr^T)  [1024,1024]
    gemm_nt_kernel<<<dim3(4, 16, 4), 256, 0, stream>>>(
        r, DGRP, DM, Wr, DGRP * DGRP, DGRP, r_hk, DGRP, DM,
        RL, DGRP, DGRP, nullptr, 0, 0, nullptr, 0, 0);

    corr_kernel<<<dim3(RL / 4, NH), 256, 0, stream>>>(r_hk, rwb, rrb, corr);

    attn_kernel<<<dim3(Q_LEN / 64, BSZ * NH), 256, 0, stream>>>(
        head_q, head_k, head_v, r_hk, corr, rwb, attn_o);

    // inter -> tmp  [2048,256]
    gemm_nt_kernel<<<dim3(4, 32, 1), 256, 0, stream>>>(
        attn_o, 0, DM, Winter, 0, DM, tmp, 0, DGRP, Q_LEN * BSZ, DGRP, DM,
        nullptr, 0, 0, nullptr, 0, 0);
    // out = grouped(attn_o * Wintra^T) + inter + w
    gemm_nt_kernel<<<dim3(4, 32, 4), 256, 0, stream>>>(
        attn_o, DGRP, DM, Wintra, DGRP * DGRP, DGRP, out, DGRP, DM,
        Q_LEN * BSZ, DGRP, DGRP, tmp, 0, DGRP, w, DGRP, DM);
}

// Round 6
// 517.909 us; speedup vs baseline: 1.6156x; 1.6156x over previous
//
#include <hip/hip_runtime.h>
#include <math.h>

#define Q_LEN 512
#define M_LEN 512
#define KL    1024
#define BSZ   4
#define DM    1024
#define NH    16
#define DHD   64
#define NG    4
#define DGRP  256
#define RL    1024
#define LN_EPS 1e-6f
#define ATT_SCALE 0.125f

typedef short s16x8 __attribute__((ext_vector_type(8)));
typedef float f32x4 __attribute__((ext_vector_type(4)));

__device__ __forceinline__ float wave_sum64(float v) {
#pragma unroll
    for (int off = 32; off > 0; off >>= 1) v += __shfl_xor(v, off);
    return v;
}

__device__ __forceinline__ ushort f2bf(float f) {
    unsigned u = __float_as_uint(f);
    unsigned r = (u + 0x7fffu + ((u >> 16) & 1u)) >> 16;   // RNE
    return (ushort)r;
}

// ---------------- f32 -> bf16 cast (n multiple of 1024) ----------------
__global__ __launch_bounds__(256) void cast_kernel(
    const float* __restrict__ src, ushort* __restrict__ dst)
{
    int i = (blockIdx.x * 256 + threadIdx.x) * 4;
    float4 v = *(const float4*)(src + i);
    ushort4 o;
    o.x = f2bf(v.x); o.y = f2bf(v.y); o.z = f2bf(v.z); o.w = f2bf(v.w);
    *(ushort4*)(dst + i) = o;
}

// ---------------- group LayerNorm for w (G=4 groups of 256) -> bf16 --------
__global__ __launch_bounds__(64) void group_ln_kernel(
    const float* __restrict__ w, const float* __restrict__ gamma,
    const float* __restrict__ beta, ushort* __restrict__ out)
{
    int bid = blockIdx.x;              // (q*BSZ + b)*NG + g
    int g = bid & (NG - 1);
    long long row = bid >> 2;
    int t = threadIdx.x;
    long long base = row * DM + g * DGRP + t * 4;
    float4 x = *(const float4*)(w + base);
    float mean = wave_sum64(x.x + x.y + x.z + x.w) * (1.0f / 256.0f);
    float dx = x.x - mean, dy = x.y - mean, dz = x.z - mean, dw = x.w - mean;
    float ss = wave_sum64(dx * dx + dy * dy + dz * dz + dw * dw);
    float inv = 1.0f / (sqrtf(ss * (1.0f / 255.0f)) + LN_EPS);   // ddof=1
    int db = g * DGRP + t * 4;
    float4 ga = *(const float4*)(gamma + db);
    float4 be = *(const float4*)(beta + db);
    ushort4 o;
    o.x = f2bf(ga.x * (dx * inv) + be.x);
    o.y = f2bf(ga.y * (dy * inv) + be.y);
    o.z = f2bf(ga.z * (dz * inv) + be.z);
    o.w = f2bf(ga.w * (dw * inv) + be.w);
    *(ushort4*)(out + base) = o;
}

// ---------------- full LayerNorm for kv = concat(mems, w) -> bf16 ----------
__global__ __launch_bounds__(256) void kv_ln_kernel(
    const float* __restrict__ mems, const float* __restrict__ w,
    const float* __restrict__ gamma, const float* __restrict__ beta,
    ushort* __restrict__ out)
{
    int row = blockIdx.x;              // k*BSZ + b
    int k = row >> 2, b = row & 3;
    const float* src = (k < M_LEN) ? (mems + ((long long)k * BSZ + b) * DM)
                                   : (w + ((long long)(k - M_LEN) * BSZ + b) * DM);
    int t = threadIdx.x;
    float4 x = *(const float4*)(src + t * 4);
    __shared__ float red[4];
    float s = wave_sum64(x.x + x.y + x.z + x.w);
    int wv = t >> 6, ln = t & 63;
    if (ln == 0) red[wv] = s;
    __syncthreads();
    float mean = (red[0] + red[1] + red[2] + red[3]) * (1.0f / 1024.0f);
    float dx = x.x - mean, dy = x.y - mean, dz = x.z - mean, dw = x.w - mean;
    float ss = wave_sum64(dx * dx + dy * dy + dz * dz + dw * dw);
    __syncthreads();
    if (ln == 0) red[wv] = ss;
    __syncthreads();
    float var = (red[0] + red[1] + red[2] + red[3]) * (1.0f / 1023.0f);
    float inv = 1.0f / (sqrtf(var) + LN_EPS);
    int db = t * 4;
    float4 ga = *(const float4*)(gamma + db);
    float4 be = *(const float4*)(beta + db);
    ushort4 o;
    o.x = f2bf(ga.x * (dx * inv) + be.x);
    o.y = f2bf(ga.y * (dy * inv) + be.y);
    o.z = f2bf(ga.z * (dz * inv) + be.z);
    o.w = f2bf(ga.w * (dw * inv) + be.w);
    *(ushort4*)(out + (long long)row * DM + db) = o;
}

// ------ bf16 MFMA GEMM  C[M,N] = A[M,K] * W[N,K]^T  (f32 out, +add1 +add2) -
// 64x64 tile, 4 waves (2x2 of 32x32), K-step 32, 16x16x32 MFMA.
// M,N multiples of 64; K multiple of 32.
__global__ __launch_bounds__(256) void gemm_bf16_nt(
    const ushort* __restrict__ A, long long aZ, int lda,
    const ushort* __restrict__ W, long long wZ, int ldw,
    float* __restrict__ C, long long cZ, int ldc,
    int M, int N, int K,
    const float* __restrict__ add1, long long a1Z, int lda1,
    const float* __restrict__ add2, long long a2Z, int lda2)
{
    int z = blockIdx.z;
    A += (long long)z * aZ;
    W += (long long)z * wZ;
    C += (long long)z * cZ;
    if (add1) add1 += (long long)z * a1Z;
    if (add2) add2 += (long long)z * a2Z;
    int m0 = blockIdx.y * 64, n0 = blockIdx.x * 64;
    int t = threadIdx.x;
    int lane = t & 63, wid = t >> 6;
    int wr = wid >> 1, wc = wid & 1;         // wave's 32x32 quadrant
    int srow = t >> 2, scol = (t & 3) * 8;   // staging: 1 x short8 per thread
    int fr = lane & 15, kq = (lane >> 4) * 8;

    __shared__ __align__(16) ushort As[64][40];   // +8 pad: 2-way banks (free)
    __shared__ __align__(16) ushort Ws[64][40];

    f32x4 acc00 = {}, acc01 = {}, acc10 = {}, acc11 = {};

    for (int k0 = 0; k0 < K; k0 += 32) {
        *(s16x8*)&As[srow][scol] =
            *(const s16x8*)(A + (long long)(m0 + srow) * lda + k0 + scol);
        *(s16x8*)&Ws[srow][scol] =
            *(const s16x8*)(W + (long long)(n0 + srow) * ldw + k0 + scol);
        __syncthreads();
        s16x8 a0 = *(const s16x8*)&As[wr * 32 + fr][kq];
        s16x8 a1 = *(const s16x8*)&As[wr * 32 + 16 + fr][kq];
        s16x8 b0 = *(const s16x8*)&Ws[wc * 32 + fr][kq];
        s16x8 b1 = *(const s16x8*)&Ws[wc * 32 + 16 + fr][kq];
        acc00 = __builtin_amdgcn_mfma_f32_16x16x32_bf16(a0, b0, acc00, 0, 0, 0);
        acc01 = __builtin_amdgcn_mfma_f32_16x16x32_bf16(a0, b1, acc01, 0, 0, 0);
        acc10 = __builtin_amdgcn_mfma_f32_16x16x32_bf16(a1, b0, acc10, 0, 0, 0);
        acc11 = __builtin_amdgcn_mfma_f32_16x16x32_bf16(a1, b1, acc11, 0, 0, 0);
        __syncthreads();
    }

    // C/D layout: col = lane&15, row = (lane>>4)*4 + reg   [m89]
    int rbase = (lane >> 4) * 4;
#pragma unroll
    for (int p = 0; p < 4; ++p) {
        int mrow0 = wr * 32 + rbase + p;
        int mrow1 = mrow0 + 16;
        int ncol0 = wc * 32 + fr;
        int ncol1 = ncol0 + 16;
        float v00 = acc00[p], v01 = acc01[p], v10 = acc10[p], v11 = acc11[p];
        long long r0 = m0 + mrow0, r1 = m0 + mrow1;
        int c0 = n0 + ncol0, c1 = n0 + ncol1;
        if (add1) {
            v00 += add1[r0 * lda1 + c0]; v01 += add1[r0 * lda1 + c1];
            v10 += add1[r1 * lda1 + c0]; v11 += add1[r1 * lda1 + c1];
        }
        if (add2) {
            v00 += add2[r0 * lda2 + c0]; v01 += add2[r0 * lda2 + c1];
            v10 += add2[r1 * lda2 + c0]; v11 += add2[r1 * lda2 + c1];
        }
        C[r0 * ldc + c0] = v00; C[r0 * ldc + c1] = v01;
        C[r1 * ldc + c0] = v10; C[r1 * ldc + c1] = v11;
    }
}

// --------- corr[n,k] = sum_d (rrb[n,d]-rwb[n,d]) * r_head_k[k,n,d] ---------
__global__ __launch_bounds__(256) void corr_kernel(
    const float* __restrict__ r_hk, const float* __restrict__ rwb,
    const float* __restrict__ rrb, float* __restrict__ corr)
{
    int n = blockIdx.y;
    int k = blockIdx.x * 4 + (threadIdx.x >> 6);
    int d = threadIdx.x & 63;
    float diff = rrb[n * DHD + d] - rwb[n * DHD + d];
    float v = diff * r_hk[(long long)k * DM + n * DHD + d];
    v = wave_sum64(v);
    if (d == 0) corr[n * RL + k] = v;
}

// ---------------- flash-style rel-shift attention (f32) ----------------
__global__ __launch_bounds__(256) void attn_kernel(
    const float* __restrict__ head_q, const float* __restrict__ head_k,
    const float* __restrict__ head_v, const float* __restrict__ r_hk,
    const float* __restrict__ corr, const float* __restrict__ rwb,
    ushort* __restrict__ attn_out)
{
    __shared__ float QsT[64][68];     // [d][i]  (q + r_w_bias)
    __shared__ float KsT[64][68];     // [d][j]
    __shared__ float Vs[64][68];      // [j][d]
    __shared__ float Ps[64][68];      // [i][j]
    __shared__ float RKsT[64][132];   // [d][kk], kk in [0,128)
    __shared__ float BDs[64][128];    // [i][kk]
    __shared__ float corrS[128];

    int bh = blockIdx.y;
    int b = bh >> 4, n = bh & 15;
    int i0 = blockIdx.x * 64;
    int t = threadIdx.x;
    int tr = t >> 4, tc = t & 15;
    int lr = t >> 2, lc = (t & 3) * 4;

    {   // stage Q tile once, adding r_w_bias
        const float* qsrc = head_q + ((long long)(i0 + lr) * BSZ + b) * DM + n * DHD;
#pragma unroll
        for (int rr = 0; rr < 4; ++rr) {
            int c = lc + 16 * rr;
            float4 v = *(const float4*)(qsrc + c);
            float4 bi = *(const float4*)(rwb + n * DHD + c);
            QsT[c + 0][lr] = v.x + bi.x;
            QsT[c + 1][lr] = v.y + bi.y;
            QsT[c + 2][lr] = v.z + bi.z;
            QsT[c + 3][lr] = v.w + bi.w;
        }
    }

    float m_[4], l_[4], O_[4][4];
#pragma unroll
    for (int ii = 0; ii < 4; ++ii) {
        m_[ii] = -INFINITY; l_[ii] = 0.0f;
#pragma unroll
        for (int jj = 0; jj < 4; ++jj) O_[ii][jj] = 0.0f;
    }

    int nJ = ((i0 + 575) >> 6) + 1;
    if (nJ > 16) nJ = 16;

    for (int jt = 0; jt < nJ; ++jt) {
        int j0 = jt * 64;
        int ka = j0 + 448 - i0;
        {
            const float* ksrc = head_k + ((long long)(j0 + lr) * BSZ + b) * DM + n * DHD;
            const float* vsrc = head_v + ((long long)(j0 + lr) * BSZ + b) * DM + n * DHD;
#pragma unroll
            for (int rr = 0; rr < 4; ++rr) {
                int c = lc + 16 * rr;
                float4 kv4 = *(const float4*)(ksrc + c);
                KsT[c + 0][lr] = kv4.x;
                KsT[c + 1][lr] = kv4.y;
                KsT[c + 2][lr] = kv4.z;
                KsT[c + 3][lr] = kv4.w;
                *(float4*)&Vs[lr][c] = *(const float4*)(vsrc + c);
            }
#pragma unroll
            for (int half = 0; half < 2; ++half) {
                int rrow = lr + half * 64;
                int kidx = ka + rrow;
                bool ok = (kidx >= 0) && (kidx < RL);
                const float* rsrc = r_hk + (long long)kidx * DM + n * DHD;
#pragma unroll
                for (int rr = 0; rr < 4; ++rr) {
                    int c = lc + 16 * rr;
                    float4 v4 = ok ? *(const float4*)(rsrc + c) : make_float4(0.f, 0.f, 0.f, 0.f);
                    RKsT[c + 0][rrow] = v4.x;
                    RKsT[c + 1][rrow] = v4.y;
                    RKsT[c + 2][rrow] = v4.z;
                    RKsT[c + 3][rrow] = v4.w;
                }
            }
            if (t < 128) {
                int kidx = ka + t;
                corrS[t] = (kidx >= 0 && kidx < RL) ? corr[n * RL + kidx] : 0.0f;
            }
        }
        __syncthreads();

        float ac[4][4] = {};
        float bd0[4][4] = {};
        float bd1[4][4] = {};
        for (int d = 0; d < DHD; ++d) {
            float q4[4], k4[4], ra[4], rb[4];
            *(float4*)q4 = *(const float4*)&QsT[d][tr * 4];
            *(float4*)k4 = *(const float4*)&KsT[d][tc * 4];
            *(float4*)ra = *(const float4*)&RKsT[d][tc * 4];
            *(float4*)rb = *(const float4*)&RKsT[d][64 + tc * 4];
#pragma unroll
            for (int ii = 0; ii < 4; ++ii)
#pragma unroll
                for (int jj = 0; jj < 4; ++jj) {
                    ac[ii][jj] += q4[ii] * k4[jj];
                    bd0[ii][jj] += q4[ii] * ra[jj];
                    bd1[ii][jj] += q4[ii] * rb[jj];
                }
        }
#pragma unroll
        for (int ii = 0; ii < 4; ++ii)
#pragma unroll
            for (int jj = 0; jj < 4; ++jj) {
                BDs[tr * 4 + ii][tc * 4 + jj] = bd0[ii][jj] + corrS[tc * 4 + jj];
                BDs[tr * 4 + ii][64 + tc * 4 + jj] = bd1[ii][jj] + corrS[64 + tc * 4 + jj];
            }
        __syncthreads();

#pragma unroll
        for (int ii = 0; ii < 4; ++ii) {
            int i = i0 + tr * 4 + ii;
            float pv[4];
            float rowm = -INFINITY;
#pragma unroll
            for (int jj = 0; jj < 4; ++jj) {
                int j = j0 + tc * 4 + jj;
                float s = -INFINITY;
                if (j <= i + M_LEN) {
                    int kk = 63 + (tc * 4 + jj) - (tr * 4 + ii);
                    s = (ac[ii][jj] + BDs[tr * 4 + ii][kk]) * ATT_SCALE;
                }
                pv[jj] = s;
                rowm = fmaxf(rowm, s);
            }
            rowm = fmaxf(rowm, __shfl_xor(rowm, 1));
            rowm = fmaxf(rowm, __shfl_xor(rowm, 2));
            rowm = fmaxf(rowm, __shfl_xor(rowm, 4));
            rowm = fmaxf(rowm, __shfl_xor(rowm, 8));
            float newm = fmaxf(m_[ii], rowm);
            float alpha = __expf(m_[ii] - newm);
            float rs = 0.0f;
#pragma unroll
            for (int jj = 0; jj < 4; ++jj) {
                float p = __expf(pv[jj] - newm);
                rs += p;
                Ps[tr * 4 + ii][tc * 4 + jj] = p;
            }
            rs += __shfl_xor(rs, 1);
            rs += __shfl_xor(rs, 2);
            rs += __shfl_xor(rs, 4);
            rs += __shfl_xor(rs, 8);
            l_[ii] = l_[ii] * alpha + rs;
            m_[ii] = newm;
#pragma unroll
            for (int jj = 0; jj < 4; ++jj) O_[ii][jj] *= alpha;
        }
        __syncthreads();

        for (int j = 0; j < 64; ++j) {
            float v4[4];
            *(float4*)v4 = *(const float4*)&Vs[j][tc * 4];
#pragma unroll
            for (int ii = 0; ii < 4; ++ii) {
                float p = Ps[tr * 4 + ii][j];
#pragma unroll
                for (int jj = 0; jj < 4; ++jj) O_[ii][jj] += p * v4[jj];
            }
        }
        __syncthreads();
    }

#pragma unroll
    for (int ii = 0; ii < 4; ++ii) {
        long long i = i0 + tr * 4 + ii;
        float invl = 1.0f / l_[ii];
        ushort4 o4;
        o4.x = f2bf(O_[ii][0] * invl);
        o4.y = f2bf(O_[ii][1] * invl);
        o4.z = f2bf(O_[ii][2] * invl);
        o4.w = f2bf(O_[ii][3] * invl);
        *(ushort4*)(attn_out + (i * BSZ + b) * DM + n * DHD + tc * 4) = o4;
    }
}

extern "C" void kernel_launch(void* const* d_in, const int* in_sizes, int n_in,
                              void* d_out, int out_size, void* d_ws, size_t ws_size,
                              hipStream_t stream) {
    const float* w       = (const float*)d_in[0];
    const float* r       = (const float*)d_in[1];
    const float* rwb     = (const float*)d_in[2];
    const float* rrb     = (const float*)d_in[3];
    const float* mems    = (const float*)d_in[4];
    const float* gamma_q = (const float*)d_in[5];
    const float* beta_q  = (const float*)d_in[6];
    const float* gamma_kv= (const float*)d_in[7];
    const float* beta_kv = (const float*)d_in[8];
    const float* Wq      = (const float*)d_in[9];
    const float* Wiq     = (const float*)d_in[10];
    const float* Wk      = (const float*)d_in[11];
    const float* Wv      = (const float*)d_in[12];
    const float* Wr      = (const float*)d_in[13];
    const float* Wintra  = (const float*)d_in[14];
    const float* Winter  = (const float*)d_in[15];
    float* out = (float*)d_out;
    float* ws = (float*)d_ws;

    float* head_q = ws;                       // 2,097,152
    float* head_k = head_q + 2097152;         // 4,194,304
    float* head_v = head_k + 4194304;         // 4,194,304
    float* r_hk   = head_v + 4194304;         // 1,048,576
    float* corr   = r_hk + 1048576;           // 16,384
    float* tmp    = corr + 16384;             // 524,288 (q_global, then inter)

    ushort* bfb        = (ushort*)(tmp + 524288);
    ushort* w_norm_bf  = bfb;                 // 2,097,152
    ushort* kv_norm_bf = w_norm_bf + 2097152; // 4,194,304
    ushort* attn_o_bf  = kv_norm_bf + 4194304;// 2,097,152
    ushort* r_bf       = attn_o_bf + 2097152; // 1,048,576
    ushort* Wk_bf      = r_bf + 1048576;      // 1,048,576
    ushort* Wv_bf      = Wk_bf + 1048576;     // 1,048,576
    ushort* Wq_bf      = Wv_bf + 1048576;     // 262,144
    ushort* Wiq_bf     = Wq_bf + 262144;      // 262,144
    ushort* Wr_bf      = Wiq_bf + 262144;     // 262,144
    ushort* Wintra_bf  = Wr_bf + 262144;      // 262,144
    ushort* Winter_bf  = Wintra_bf + 262144;  // 262,144

    group_ln_kernel<<<dim3(Q_LEN * BSZ * NG), 64, 0, stream>>>(w, gamma_q, beta_q, w_norm_bf);
    kv_ln_kernel<<<dim3(KL * BSZ), 256, 0, stream>>>(mems, w, gamma_kv, beta_kv, kv_norm_bf);

    cast_kernel<<<dim3(1024), 256, 0, stream>>>(r, r_bf);
    cast_kernel<<<dim3(1024), 256, 0, stream>>>(Wk, Wk_bf);
    cast_kernel<<<dim3(1024), 256, 0, stream>>>(Wv, Wv_bf);
    cast_kernel<<<dim3(256), 256, 0, stream>>>(Wq, Wq_bf);
    cast_kernel<<<dim3(256), 256, 0, stream>>>(Wiq, Wiq_bf);
    cast_kernel<<<dim3(256), 256, 0, stream>>>(Wr, Wr_bf);
    cast_kernel<<<dim3(256), 256, 0, stream>>>(Wintra, Wintra_bf);
    cast_kernel<<<dim3(256), 256, 0, stream>>>(Winter, Winter_bf);

    // head_k = kv_norm * Wk^T   [4096,1024]x[1024,1024]
    gemm_bf16_nt<<<dim3(16, 64, 1), 256, 0, stream>>>(
        kv_norm_bf, 0, DM, Wk_bf, 0, DM, head_k, 0, DM, KL * BSZ, DM, DM,
        nullptr, 0, 0, nullptr, 0, 0);
    // head_v = kv_norm * Wv^T
    gemm_bf16_nt<<<dim3(16, 64, 1), 256, 0, stream>>>(
        kv_norm_bf, 0, DM, Wv_bf, 0, DM, head_v, 0, DM, KL * BSZ, DM, DM,
        nullptr, 0, 0, nullptr, 0, 0);
    // q_global -> tmp  [2048,256]
    gemm_bf16_nt<<<dim3(4, 32, 1), 256, 0, stream>>>(
        w_norm_bf, 0, DM, Wiq_bf, 0, DM, tmp, 0, DGRP, Q_LEN * BSZ, DGRP, DM,
        nullptr, 0, 0, nullptr, 0, 0);
    // head_q = grouped(w_norm * Wq^T) + q_global   (z = group)
    gemm_bf16_nt<<<dim3(4, 32, 4), 256, 0, stream>>>(
        w_norm_bf, DGRP, DM, Wq_bf, DGRP * DGRP, DGRP, head_q, DGRP, DM,
        Q_LEN * BSZ, DGRP, DGRP, tmp, 0, DGRP, nullptr, 0, 0);
    // r_head_k = grouped(r * Wr^T)  [1024,1024]
    gemm_bf16_nt<<<dim3(4, 16, 4), 256, 0, stream>>>(
        r_bf, DGRP, DM, Wr_bf, DGRP * DGRP, DGRP, r_hk, DGRP, DM,
        RL, DGRP, DGRP, nullptr, 0, 0, nullptr, 0, 0);

    corr_kernel<<<dim3(RL / 4, NH), 256, 0, stream>>>(r_hk, rwb, rrb, corr);

    attn_kernel<<<dim3(Q_LEN / 64, BSZ * NH), 256, 0, stream>>>(
        head_q, head_k, head_v, r_hk, corr, rwb, attn_o_bf);

    // inter -> tmp  [2048,256]
    gemm_bf16_nt<<<dim3(4, 32, 1), 256, 0, stream>>>(
        attn_o_bf, 0, DM, Winter_bf, 0, DM, tmp, 0, DGRP, Q_LEN * BSZ, DGRP, DM,
        nullptr, 0, 0, nullptr, 0, 0);
    // out = grouped(attn_o * Wintra^T) + inter + w
    gemm_bf16_nt<<<dim3(4, 32, 4), 256, 0, stream>>>(
        attn_o_bf, DGRP, DM, Wintra_bf, DGRP * DGRP, DGRP, out, DGRP, DM,
        Q_LEN * BSZ, DGRP, DGRP, tmp, 0, DGRP, w, DGRP, DM);
}

// Round 7
// 218.045 us; speedup vs baseline: 3.8375x; 2.3752x over previous
//
#include <hip/hip_runtime.h>
#include <math.h>

#define Q_LEN 512
#define M_LEN 512
#define KL    1024
#define BSZ   4
#define DM    1024
#define NH    16
#define DHD   64
#define NG    4
#define DGRP  256
#define RL    1024
#define LN_EPS 1e-6f
#define ATT_SCALE 0.125f

typedef short s16x8 __attribute__((ext_vector_type(8)));
typedef float f32x4 __attribute__((ext_vector_type(4)));

__device__ __forceinline__ float wave_sum64(float v) {
#pragma unroll
    for (int off = 32; off > 0; off >>= 1) v += __shfl_xor(v, off);
    return v;
}

__device__ __forceinline__ ushort f2bf(float f) {
    unsigned u = __float_as_uint(f);
    unsigned r = (u + 0x7fffu + ((u >> 16) & 1u)) >> 16;   // RNE
    return (ushort)r;
}
__device__ __forceinline__ float bf2f(ushort u) {
    return __uint_as_float(((unsigned)u) << 16);
}

// ---------------- f32 -> bf16 cast (n multiple of 1024) ----------------
__global__ __launch_bounds__(256) void cast_kernel(
    const float* __restrict__ src, ushort* __restrict__ dst)
{
    int i = (blockIdx.x * 256 + threadIdx.x) * 4;
    float4 v = *(const float4*)(src + i);
    ushort4 o;
    o.x = f2bf(v.x); o.y = f2bf(v.y); o.z = f2bf(v.z); o.w = f2bf(v.w);
    *(ushort4*)(dst + i) = o;
}

// ---------------- group LayerNorm for w (G=4 groups of 256) -> bf16 --------
__global__ __launch_bounds__(64) void group_ln_kernel(
    const float* __restrict__ w, const float* __restrict__ gamma,
    const float* __restrict__ beta, ushort* __restrict__ out)
{
    int bid = blockIdx.x;              // (q*BSZ + b)*NG + g
    int g = bid & (NG - 1);
    long long row = bid >> 2;
    int t = threadIdx.x;
    long long base = row * DM + g * DGRP + t * 4;
    float4 x = *(const float4*)(w + base);
    float mean = wave_sum64(x.x + x.y + x.z + x.w) * (1.0f / 256.0f);
    float dx = x.x - mean, dy = x.y - mean, dz = x.z - mean, dw = x.w - mean;
    float ss = wave_sum64(dx * dx + dy * dy + dz * dz + dw * dw);
    float inv = 1.0f / (sqrtf(ss * (1.0f / 255.0f)) + LN_EPS);   // ddof=1
    int db = g * DGRP + t * 4;
    float4 ga = *(const float4*)(gamma + db);
    float4 be = *(const float4*)(beta + db);
    ushort4 o;
    o.x = f2bf(ga.x * (dx * inv) + be.x);
    o.y = f2bf(ga.y * (dy * inv) + be.y);
    o.z = f2bf(ga.z * (dz * inv) + be.z);
    o.w = f2bf(ga.w * (dw * inv) + be.w);
    *(ushort4*)(out + base) = o;
}

// ---------------- full LayerNorm for kv = concat(mems, w) -> bf16 ----------
__global__ __launch_bounds__(256) void kv_ln_kernel(
    const float* __restrict__ mems, const float* __restrict__ w,
    const float* __restrict__ gamma, const float* __restrict__ beta,
    ushort* __restrict__ out)
{
    int row = blockIdx.x;              // k*BSZ + b
    int k = row >> 2, b = row & 3;
    const float* src = (k < M_LEN) ? (mems + ((long long)k * BSZ + b) * DM)
                                   : (w + ((long long)(k - M_LEN) * BSZ + b) * DM);
    int t = threadIdx.x;
    float4 x = *(const float4*)(src + t * 4);
    __shared__ float red[4];
    float s = wave_sum64(x.x + x.y + x.z + x.w);
    int wv = t >> 6, ln = t & 63;
    if (ln == 0) red[wv] = s;
    __syncthreads();
    float mean = (red[0] + red[1] + red[2] + red[3]) * (1.0f / 1024.0f);
    float dx = x.x - mean, dy = x.y - mean, dz = x.z - mean, dw = x.w - mean;
    float ss = wave_sum64(dx * dx + dy * dy + dz * dz + dw * dw);
    __syncthreads();
    if (ln == 0) red[wv] = ss;
    __syncthreads();
    float var = (red[0] + red[1] + red[2] + red[3]) * (1.0f / 1023.0f);
    float inv = 1.0f / (sqrtf(var) + LN_EPS);
    int db = t * 4;
    float4 ga = *(const float4*)(gamma + db);
    float4 be = *(const float4*)(beta + db);
    ushort4 o;
    o.x = f2bf(ga.x * (dx * inv) + be.x);
    o.y = f2bf(ga.y * (dy * inv) + be.y);
    o.z = f2bf(ga.z * (dz * inv) + be.z);
    o.w = f2bf(ga.w * (dw * inv) + be.w);
    *(ushort4*)(out + (long long)row * DM + db) = o;
}

// ------ bf16 MFMA GEMM  C = A[M,K] * W[N,K]^T  (+add1 +add2), f32 or bf16 out
__global__ __launch_bounds__(256) void gemm_bf16_nt(
    const ushort* __restrict__ A, long long aZ, int lda,
    const ushort* __restrict__ W, long long wZ, int ldw,
    float* __restrict__ C, ushort* __restrict__ Cb, long long cZ, int ldc,
    int M, int N, int K,
    const float* __restrict__ add1, long long a1Z, int lda1,
    const float* __restrict__ add2, long long a2Z, int lda2)
{
    int z = blockIdx.z;
    A += (long long)z * aZ;
    W += (long long)z * wZ;
    if (C)  C += (long long)z * cZ;
    if (Cb) Cb += (long long)z * cZ;
    if (add1) add1 += (long long)z * a1Z;
    if (add2) add2 += (long long)z * a2Z;
    int m0 = blockIdx.y * 64, n0 = blockIdx.x * 64;
    int t = threadIdx.x;
    int lane = t & 63, wid = t >> 6;
    int wr = wid >> 1, wc = wid & 1;         // wave's 32x32 quadrant
    int srow = t >> 2, scol = (t & 3) * 8;   // staging: 1 x short8 per thread
    int fr = lane & 15, kq = (lane >> 4) * 8;

    __shared__ __align__(16) ushort As[64][40];
    __shared__ __align__(16) ushort Ws[64][40];

    f32x4 acc00 = {}, acc01 = {}, acc10 = {}, acc11 = {};

    for (int k0 = 0; k0 < K; k0 += 32) {
        *(s16x8*)&As[srow][scol] =
            *(const s16x8*)(A + (long long)(m0 + srow) * lda + k0 + scol);
        *(s16x8*)&Ws[srow][scol] =
            *(const s16x8*)(W + (long long)(n0 + srow) * ldw + k0 + scol);
        __syncthreads();
        s16x8 a0 = *(const s16x8*)&As[wr * 32 + fr][kq];
        s16x8 a1 = *(const s16x8*)&As[wr * 32 + 16 + fr][kq];
        s16x8 b0 = *(const s16x8*)&Ws[wc * 32 + fr][kq];
        s16x8 b1 = *(const s16x8*)&Ws[wc * 32 + 16 + fr][kq];
        acc00 = __builtin_amdgcn_mfma_f32_16x16x32_bf16(a0, b0, acc00, 0, 0, 0);
        acc01 = __builtin_amdgcn_mfma_f32_16x16x32_bf16(a0, b1, acc01, 0, 0, 0);
        acc10 = __builtin_amdgcn_mfma_f32_16x16x32_bf16(a1, b0, acc10, 0, 0, 0);
        acc11 = __builtin_amdgcn_mfma_f32_16x16x32_bf16(a1, b1, acc11, 0, 0, 0);
        __syncthreads();
    }

    // C/D layout: col = lane&15, row = (lane>>4)*4 + reg   [verified R6]
    int rbase = (lane >> 4) * 4;
#pragma unroll
    for (int p = 0; p < 4; ++p) {
        int mrow0 = wr * 32 + rbase + p;
        int mrow1 = mrow0 + 16;
        int ncol0 = wc * 32 + fr;
        int ncol1 = ncol0 + 16;
        float v00 = acc00[p], v01 = acc01[p], v10 = acc10[p], v11 = acc11[p];
        long long r0 = m0 + mrow0, r1 = m0 + mrow1;
        int c0 = n0 + ncol0, c1 = n0 + ncol1;
        if (add1) {
            v00 += add1[r0 * lda1 + c0]; v01 += add1[r0 * lda1 + c1];
            v10 += add1[r1 * lda1 + c0]; v11 += add1[r1 * lda1 + c1];
        }
        if (add2) {
            v00 += add2[r0 * lda2 + c0]; v01 += add2[r0 * lda2 + c1];
            v10 += add2[r1 * lda2 + c0]; v11 += add2[r1 * lda2 + c1];
        }
        if (Cb) {
            Cb[r0 * ldc + c0] = f2bf(v00); Cb[r0 * ldc + c1] = f2bf(v01);
            Cb[r1 * ldc + c0] = f2bf(v10); Cb[r1 * ldc + c1] = f2bf(v11);
        } else {
            C[r0 * ldc + c0] = v00; C[r0 * ldc + c1] = v01;
            C[r1 * ldc + c0] = v10; C[r1 * ldc + c1] = v11;
        }
    }
}

// --------- transpose head_v: [k*4+b][n*64+d] -> [(b*16+n)*64+d][k] ---------
__global__ __launch_bounds__(256) void transpose_v_kernel(
    const ushort* __restrict__ vin, ushort* __restrict__ vout)
{
    __shared__ __align__(16) ushort T[64][72];
    int bn = blockIdx.y;               // b*16+n
    int b = bn >> 4, n = bn & 15;
    int k0 = blockIdx.x * 64;
    int t = threadIdx.x;
    {
        int kr = t >> 2, dp = (t & 3) * 16;
        const ushort* sp = vin + (((long long)(k0 + kr)) * 4 + b) * DM + n * DHD + dp;
        *(s16x8*)&T[kr][dp] = *(const s16x8*)sp;
        *(s16x8*)&T[kr][dp + 8] = *(const s16x8*)(sp + 8);
    }
    __syncthreads();
    {
        int d = t >> 2, kp = (t & 3) * 16;
        ushort vals[16];
#pragma unroll
        for (int q = 0; q < 16; ++q) vals[q] = T[kp + q][d];
        ushort* dp = vout + ((long long)bn * DHD + d) * KL + k0 + kp;
        *(s16x8*)dp = *(const s16x8*)&vals[0];
        *(s16x8*)(dp + 8) = *(const s16x8*)&vals[8];
    }
}

// --------- corr[n,k] = sum_d (rrb[n,d]-rwb[n,d]) * r_head_k[k,n,d] ---------
__global__ __launch_bounds__(256) void corr_kernel(
    const ushort* __restrict__ r_hk, const float* __restrict__ rwb,
    const float* __restrict__ rrb, float* __restrict__ corr)
{
    int n = blockIdx.y;
    int k = blockIdx.x * 4 + (threadIdx.x >> 6);
    int d = threadIdx.x & 63;
    float diff = rrb[n * DHD + d] - rwb[n * DHD + d];
    float v = diff * bf2f(r_hk[(long long)k * DM + n * DHD + d]);
    v = wave_sum64(v);
    if (d == 0) corr[n * RL + k] = v;
}

// ---------------- MFMA flash rel-shift attention ----------------
// grid (8, 64); 256 thr = 4 waves; wave w owns q-rows [w*16, w*16+16).
// head_q already includes r_w_bias. LDS 62 KB -> 2 blocks/CU.
__global__ __launch_bounds__(256) void attn_mfma_kernel(
    const ushort* __restrict__ hq, const ushort* __restrict__ hk,
    const ushort* __restrict__ hvT, const ushort* __restrict__ rhk,
    const float* __restrict__ corr, ushort* __restrict__ attn_out)
{
    __shared__ __align__(16) ushort Ks[64][72];    // [j][d]
    __shared__ __align__(16) ushort VsT[64][72];   // [d][j]
    __shared__ __align__(16) ushort RKs[128][72];  // [kk][d]
    __shared__ __align__(16) ushort BDs[64][132];  // [i_loc][kk] bf16 (incl corr)
    __shared__ __align__(16) ushort Ps[64][72];    // [i_loc][jc] bf16
    __shared__ float corrS[128];

    int bh = blockIdx.y;
    int b = bh >> 4, n = bh & 15;
    int i0 = blockIdx.x * 64;
    int t = threadIdx.x;
    int lane = t & 63, w = t >> 6;
    int lr16 = lane & 15;            // A/B frag row
    int lk8 = (lane >> 4) * 8;       // A/B frag k offset
    int orow = (lane >> 4) * 4;      // C/D row base

    // Q fragments (rows w*16 + lr16), once per block
    s16x8 qf0, qf1;
    {
        const ushort* qp = hq + (((long long)(i0 + w * 16 + lr16)) * 4 + b) * DM
                              + n * DHD + lk8;
        qf0 = *(const s16x8*)qp;
        qf1 = *(const s16x8*)(qp + 32);
    }

    f32x4 O[4] = {};                 // [nb_d]; rows via reg
    float m_[4], l_[4];
#pragma unroll
    for (int r = 0; r < 4; ++r) { m_[r] = -INFINITY; l_[r] = 0.0f; }

    int nJ = ((i0 + 575) >> 6) + 1;
    if (nJ > 16) nJ = 16;

    for (int jt = 0; jt < nJ; ++jt) {
        int j0 = jt * 64;
        int ka = j0 + 448 - i0;      // window base (>=0 always)

        {   // ---- stage K, V^T, RK window, corr ----
            int row = t >> 2, dp = (t & 3) * 16;
            const ushort* kp = hk + (((long long)(j0 + row)) * 4 + b) * DM + n * DHD + dp;
            *(s16x8*)&Ks[row][dp] = *(const s16x8*)kp;
            *(s16x8*)&Ks[row][dp + 8] = *(const s16x8*)(kp + 8);
            const ushort* vp = hvT + ((long long)bh * DHD + row) * KL + j0 + dp;
            *(s16x8*)&VsT[row][dp] = *(const s16x8*)vp;
            *(s16x8*)&VsT[row][dp + 8] = *(const s16x8*)(vp + 8);
            int rr = t >> 1, dp2 = (t & 1) * 32;
            int kidx = ka + rr;
            if (kidx < RL) {
                const ushort* rp = rhk + (long long)kidx * DM + n * DHD + dp2;
#pragma unroll
                for (int q = 0; q < 4; ++q)
                    *(s16x8*)&RKs[rr][dp2 + q * 8] = *(const s16x8*)(rp + q * 8);
            } else {
                s16x8 zz = {};
#pragma unroll
                for (int q = 0; q < 4; ++q) *(s16x8*)&RKs[rr][dp2 + q * 8] = zz;
            }
            if (t < 128) corrS[t] = (ka + t < RL) ? corr[n * RL + ka + t] : 0.0f;
        }
        __syncthreads();

        // ---- AC (8 MFMA) + BD (16 MFMA) ----
        f32x4 ac[4] = {};
#pragma unroll
        for (int nb = 0; nb < 4; ++nb) {
            s16x8 kb0 = *(const s16x8*)&Ks[nb * 16 + lr16][lk8];
            s16x8 kb1 = *(const s16x8*)&Ks[nb * 16 + lr16][32 + lk8];
            ac[nb] = __builtin_amdgcn_mfma_f32_16x16x32_bf16(qf0, kb0, ac[nb], 0, 0, 0);
            ac[nb] = __builtin_amdgcn_mfma_f32_16x16x32_bf16(qf1, kb1, ac[nb], 0, 0, 0);
        }
#pragma unroll
        for (int nb = 0; nb < 8; ++nb) {
            f32x4 bd = {};
            s16x8 rb0 = *(const s16x8*)&RKs[nb * 16 + lr16][lk8];
            s16x8 rb1 = *(const s16x8*)&RKs[nb * 16 + lr16][32 + lk8];
            bd = __builtin_amdgcn_mfma_f32_16x16x32_bf16(qf0, rb0, bd, 0, 0, 0);
            bd = __builtin_amdgcn_mfma_f32_16x16x32_bf16(qf1, rb1, bd, 0, 0, 0);
            int kk = nb * 16 + lr16;
            float cadd = corrS[kk];
#pragma unroll
            for (int reg = 0; reg < 4; ++reg)
                BDs[w * 16 + orow + reg][kk] = f2bf(bd[reg] + cadd);
        }
        __syncthreads();

        // ---- rel-shift assembly + online softmax (rows via reg) ----
#pragma unroll
        for (int reg = 0; reg < 4; ++reg) {
            int il = w * 16 + orow + reg;
            int i = i0 + il;
            float pv[4];
            float rowm = -INFINITY;
#pragma unroll
            for (int nb = 0; nb < 4; ++nb) {
                int jc = nb * 16 + lr16;
                int j = j0 + jc;
                float s = -INFINITY;
                if (j <= i + M_LEN) {
                    int kk = 63 + jc - il;
                    s = (ac[nb][reg] + bf2f(BDs[il][kk])) * ATT_SCALE;
                }
                pv[nb] = s;
                rowm = fmaxf(rowm, s);
            }
            rowm = fmaxf(rowm, __shfl_xor(rowm, 1));
            rowm = fmaxf(rowm, __shfl_xor(rowm, 2));
            rowm = fmaxf(rowm, __shfl_xor(rowm, 4));
            rowm = fmaxf(rowm, __shfl_xor(rowm, 8));
            float newm = fmaxf(m_[reg], rowm);
            float alpha = __expf(m_[reg] - newm);
            float rs = 0.0f;
#pragma unroll
            for (int nb = 0; nb < 4; ++nb) {
                float p = __expf(pv[nb] - newm);
                rs += p;
                Ps[il][nb * 16 + lr16] = f2bf(p);
            }
            rs += __shfl_xor(rs, 1);
            rs += __shfl_xor(rs, 2);
            rs += __shfl_xor(rs, 4);
            rs += __shfl_xor(rs, 8);
            l_[reg] = l_[reg] * alpha + rs;
            m_[reg] = newm;
#pragma unroll
            for (int nb = 0; nb < 4; ++nb) O[nb][reg] *= alpha;
        }
        __syncthreads();

        // ---- PV (8 MFMA): O[i][d] += P[i][j] V[j][d] ----
#pragma unroll
        for (int kc = 0; kc < 2; ++kc) {
            s16x8 pa = *(const s16x8*)&Ps[w * 16 + lr16][kc * 32 + lk8];
#pragma unroll
            for (int nb = 0; nb < 4; ++nb) {
                s16x8 vb = *(const s16x8*)&VsT[nb * 16 + lr16][kc * 32 + lk8];
                O[nb] = __builtin_amdgcn_mfma_f32_16x16x32_bf16(pa, vb, O[nb], 0, 0, 0);
            }
        }
        __syncthreads();
    }

    // ---- epilogue ----
#pragma unroll
    for (int reg = 0; reg < 4; ++reg) {
        int il = w * 16 + orow + reg;
        long long i = i0 + il;
        float inv = 1.0f / l_[reg];
#pragma unroll
        for (int nb = 0; nb < 4; ++nb)
            attn_out[(i * 4 + b) * DM + n * DHD + nb * 16 + lr16] = f2bf(O[nb][reg] * inv);
    }
}

extern "C" void kernel_launch(void* const* d_in, const int* in_sizes, int n_in,
                              void* d_out, int out_size, void* d_ws, size_t ws_size,
                              hipStream_t stream) {
    const float* w       = (const float*)d_in[0];
    const float* r       = (const float*)d_in[1];
    const float* rwb     = (const float*)d_in[2];
    const float* rrb     = (const float*)d_in[3];
    const float* mems    = (const float*)d_in[4];
    const float* gamma_q = (const float*)d_in[5];
    const float* beta_q  = (const float*)d_in[6];
    const float* gamma_kv= (const float*)d_in[7];
    const float* beta_kv = (const float*)d_in[8];
    const float* Wq      = (const float*)d_in[9];
    const float* Wiq     = (const float*)d_in[10];
    const float* Wk      = (const float*)d_in[11];
    const float* Wv      = (const float*)d_in[12];
    const float* Wr      = (const float*)d_in[13];
    const float* Wintra  = (const float*)d_in[14];
    const float* Winter  = (const float*)d_in[15];
    float* out = (float*)d_out;
    float* ws = (float*)d_ws;

    float* tmp  = ws;                         // 524,288 f32 (q_global, then inter)
    float* corr = tmp + 524288;               // 16,384 f32

    ushort* w_norm_bf  = (ushort*)(corr + 16384);
    ushort* kv_norm_bf = w_norm_bf + 2097152;
    ushort* head_q_bf  = kv_norm_bf + 4194304;   // includes r_w_bias
    ushort* head_k_bf  = head_q_bf + 2097152;
    ushort* head_v_bf  = head_k_bf + 4194304;
    ushort* head_vT_bf = head_v_bf + 4194304;
    ushort* r_hk_bf    = head_vT_bf + 4194304;
    ushort* attn_o_bf  = r_hk_bf + 1048576;
    ushort* r_bf       = attn_o_bf + 2097152;
    ushort* Wk_bf      = r_bf + 1048576;
    ushort* Wv_bf      = Wk_bf + 1048576;
    ushort* Wq_bf      = Wv_bf + 1048576;
    ushort* Wiq_bf     = Wq_bf + 262144;
    ushort* Wr_bf      = Wiq_bf + 262144;
    ushort* Wintra_bf  = Wr_bf + 262144;
    ushort* Winter_bf  = Wintra_bf + 262144;

    group_ln_kernel<<<dim3(Q_LEN * BSZ * NG), 64, 0, stream>>>(w, gamma_q, beta_q, w_norm_bf);
    kv_ln_kernel<<<dim3(KL * BSZ), 256, 0, stream>>>(mems, w, gamma_kv, beta_kv, kv_norm_bf);

    cast_kernel<<<dim3(1024), 256, 0, stream>>>(r, r_bf);
    cast_kernel<<<dim3(1024), 256, 0, stream>>>(Wk, Wk_bf);
    cast_kernel<<<dim3(1024), 256, 0, stream>>>(Wv, Wv_bf);
    cast_kernel<<<dim3(256), 256, 0, stream>>>(Wq, Wq_bf);
    cast_kernel<<<dim3(256), 256, 0, stream>>>(Wiq, Wiq_bf);
    cast_kernel<<<dim3(256), 256, 0, stream>>>(Wr, Wr_bf);
    cast_kernel<<<dim3(256), 256, 0, stream>>>(Wintra, Wintra_bf);
    cast_kernel<<<dim3(256), 256, 0, stream>>>(Winter, Winter_bf);

    // head_k / head_v -> bf16
    gemm_bf16_nt<<<dim3(16, 64, 1), 256, 0, stream>>>(
        kv_norm_bf, 0, DM, Wk_bf, 0, DM, nullptr, head_k_bf, 0, DM, KL * BSZ, DM, DM,
        nullptr, 0, 0, nullptr, 0, 0);
    gemm_bf16_nt<<<dim3(16, 64, 1), 256, 0, stream>>>(
        kv_norm_bf, 0, DM, Wv_bf, 0, DM, nullptr, head_v_bf, 0, DM, KL * BSZ, DM, DM,
        nullptr, 0, 0, nullptr, 0, 0);
    transpose_v_kernel<<<dim3(16, 64), 256, 0, stream>>>(head_v_bf, head_vT_bf);

    // q_global -> tmp (f32)
    gemm_bf16_nt<<<dim3(4, 32, 1), 256, 0, stream>>>(
        w_norm_bf, 0, DM, Wiq_bf, 0, DM, tmp, nullptr, 0, DGRP, Q_LEN * BSZ, DGRP, DM,
        nullptr, 0, 0, nullptr, 0, 0);
    // head_q = grouped(w_norm*Wq^T) + q_global + rwb  -> bf16 (bias folded)
    gemm_bf16_nt<<<dim3(4, 32, 4), 256, 0, stream>>>(
        w_norm_bf, DGRP, DM, Wq_bf, DGRP * DGRP, DGRP, nullptr, head_q_bf, DGRP, DM,
        Q_LEN * BSZ, DGRP, DGRP, tmp, 0, DGRP, rwb, DGRP, 0);
    // r_head_k -> bf16
    gemm_bf16_nt<<<dim3(4, 16, 4), 256, 0, stream>>>(
        r_bf, DGRP, DM, Wr_bf, DGRP * DGRP, DGRP, nullptr, r_hk_bf, DGRP, DM,
        RL, DGRP, DGRP, nullptr, 0, 0, nullptr, 0, 0);

    corr_kernel<<<dim3(RL / 4, NH), 256, 0, stream>>>(r_hk_bf, rwb, rrb, corr);

    attn_mfma_kernel<<<dim3(Q_LEN / 64, BSZ * NH), 256, 0, stream>>>(
        head_q_bf, head_k_bf, head_vT_bf, r_hk_bf, corr, attn_o_bf);

    // inter -> tmp (f32)
    gemm_bf16_nt<<<dim3(4, 32, 1), 256, 0, stream>>>(
        attn_o_bf, 0, DM, Winter_bf, 0, DM, tmp, nullptr, 0, DGRP, Q_LEN * BSZ, DGRP, DM,
        nullptr, 0, 0, nullptr, 0, 0);
    // out = grouped(attn_o*Wintra^T) + inter + w
    gemm_bf16_nt<<<dim3(4, 32, 4), 256, 0, stream>>>(
        attn_o_bf, DGRP, DM, Wintra_bf, DGRP * DGRP, DGRP, out, nullptr, DGRP, DM,
        Q_LEN * BSZ, DGRP, DGRP, tmp, 0, DGRP, w, DGRP, DM);
}

// Round 8
// 205.034 us; speedup vs baseline: 4.0810x; 1.0635x over previous
//
#include <hip/hip_runtime.h>
#include <math.h>

#define Q_LEN 512
#define M_LEN 512
#define KL    1024
#define BSZ   4
#define DM    1024
#define NH    16
#define DHD   64
#define NG    4
#define DGRP  256
#define RL    1024
#define LN_EPS 1e-6f
#define ATT_SCALE 0.125f

typedef short s16x8 __attribute__((ext_vector_type(8)));
typedef float f32x4 __attribute__((ext_vector_type(4)));

__device__ __forceinline__ float wave_sum64(float v) {
#pragma unroll
    for (int off = 32; off > 0; off >>= 1) v += __shfl_xor(v, off);
    return v;
}

__device__ __forceinline__ ushort f2bf(float f) {
    unsigned u = __float_as_uint(f);
    unsigned r = (u + 0x7fffu + ((u >> 16) & 1u)) >> 16;   // RNE
    return (ushort)r;
}
__device__ __forceinline__ float bf2f(ushort u) {
    return __uint_as_float(((unsigned)u) << 16);
}

// ---------------- fused f32 -> bf16 cast of all 8 weight arrays ------------
__global__ __launch_bounds__(256) void cast8_kernel(
    const float* p0, const float* p1, const float* p2, const float* p3,
    const float* p4, const float* p5, const float* p6, const float* p7,
    ushort* d0, ushort* d1, ushort* d2, ushort* d3,
    ushort* d4, ushort* d5, ushort* d6, ushort* d7)
{
    int bid = blockIdx.x;
    const float* s; ushort* d; int off;
    if      (bid < 1024) { s = p0; d = d0; off = bid; }
    else if (bid < 2048) { s = p1; d = d1; off = bid - 1024; }
    else if (bid < 3072) { s = p2; d = d2; off = bid - 2048; }
    else if (bid < 3328) { s = p3; d = d3; off = bid - 3072; }
    else if (bid < 3584) { s = p4; d = d4; off = bid - 3328; }
    else if (bid < 3840) { s = p5; d = d5; off = bid - 3584; }
    else if (bid < 4096) { s = p6; d = d6; off = bid - 3840; }
    else                 { s = p7; d = d7; off = bid - 4096; }
    int i = off * 1024 + threadIdx.x * 4;
    float4 v = *(const float4*)(s + i);
    ushort4 o;
    o.x = f2bf(v.x); o.y = f2bf(v.y); o.z = f2bf(v.z); o.w = f2bf(v.w);
    *(ushort4*)(d + i) = o;
}

// ---------------- group LayerNorm for w (G=4 groups of 256) -> bf16 --------
__global__ __launch_bounds__(64) void group_ln_kernel(
    const float* __restrict__ w, const float* __restrict__ gamma,
    const float* __restrict__ beta, ushort* __restrict__ out)
{
    int bid = blockIdx.x;              // (q*BSZ + b)*NG + g
    int g = bid & (NG - 1);
    long long row = bid >> 2;
    int t = threadIdx.x;
    long long base = row * DM + g * DGRP + t * 4;
    float4 x = *(const float4*)(w + base);
    float mean = wave_sum64(x.x + x.y + x.z + x.w) * (1.0f / 256.0f);
    float dx = x.x - mean, dy = x.y - mean, dz = x.z - mean, dw = x.w - mean;
    float ss = wave_sum64(dx * dx + dy * dy + dz * dz + dw * dw);
    float inv = 1.0f / (sqrtf(ss * (1.0f / 255.0f)) + LN_EPS);   // ddof=1
    int db = g * DGRP + t * 4;
    float4 ga = *(const float4*)(gamma + db);
    float4 be = *(const float4*)(beta + db);
    ushort4 o;
    o.x = f2bf(ga.x * (dx * inv) + be.x);
    o.y = f2bf(ga.y * (dy * inv) + be.y);
    o.z = f2bf(ga.z * (dz * inv) + be.z);
    o.w = f2bf(ga.w * (dw * inv) + be.w);
    *(ushort4*)(out + base) = o;
}

// ---------------- full LayerNorm for kv = concat(mems, w) -> bf16 ----------
__global__ __launch_bounds__(256) void kv_ln_kernel(
    const float* __restrict__ mems, const float* __restrict__ w,
    const float* __restrict__ gamma, const float* __restrict__ beta,
    ushort* __restrict__ out)
{
    int row = blockIdx.x;              // k*BSZ + b
    int k = row >> 2, b = row & 3;
    const float* src = (k < M_LEN) ? (mems + ((long long)k * BSZ + b) * DM)
                                   : (w + ((long long)(k - M_LEN) * BSZ + b) * DM);
    int t = threadIdx.x;
    float4 x = *(const float4*)(src + t * 4);
    __shared__ float red[4];
    float s = wave_sum64(x.x + x.y + x.z + x.w);
    int wv = t >> 6, ln = t & 63;
    if (ln == 0) red[wv] = s;
    __syncthreads();
    float mean = (red[0] + red[1] + red[2] + red[3]) * (1.0f / 1024.0f);
    float dx = x.x - mean, dy = x.y - mean, dz = x.z - mean, dw = x.w - mean;
    float ss = wave_sum64(dx * dx + dy * dy + dz * dz + dw * dw);
    __syncthreads();
    if (ln == 0) red[wv] = ss;
    __syncthreads();
    float var = (red[0] + red[1] + red[2] + red[3]) * (1.0f / 1023.0f);
    float inv = 1.0f / (sqrtf(var) + LN_EPS);
    int db = t * 4;
    float4 ga = *(const float4*)(gamma + db);
    float4 be = *(const float4*)(beta + db);
    ushort4 o;
    o.x = f2bf(ga.x * (dx * inv) + be.x);
    o.y = f2bf(ga.y * (dy * inv) + be.y);
    o.z = f2bf(ga.z * (dz * inv) + be.z);
    o.w = f2bf(ga.w * (dw * inv) + be.w);
    *(ushort4*)(out + (long long)row * DM + db) = o;
}

// ------ bf16 MFMA GEMM  C = A[M,K] * W[N,K]^T  (+add1 +add2), f32 or bf16 out
__global__ __launch_bounds__(256) void gemm_bf16_nt(
    const ushort* __restrict__ A, long long aZ, int lda,
    const ushort* __restrict__ W, long long wZ, int ldw,
    float* __restrict__ C, ushort* __restrict__ Cb, long long cZ, int ldc,
    int M, int N, int K,
    const float* __restrict__ add1, long long a1Z, int lda1,
    const float* __restrict__ add2, long long a2Z, int lda2)
{
    int z = blockIdx.z;
    A += (long long)z * aZ;
    W += (long long)z * wZ;
    if (C)  C += (long long)z * cZ;
    if (Cb) Cb += (long long)z * cZ;
    if (add1) add1 += (long long)z * a1Z;
    if (add2) add2 += (long long)z * a2Z;
    int m0 = blockIdx.y * 64, n0 = blockIdx.x * 64;
    int t = threadIdx.x;
    int lane = t & 63, wid = t >> 6;
    int wr = wid >> 1, wc = wid & 1;
    int srow = t >> 2, scol = (t & 3) * 8;
    int fr = lane & 15, kq = (lane >> 4) * 8;

    __shared__ __align__(16) ushort As[64][40];
    __shared__ __align__(16) ushort Ws[64][40];

    f32x4 acc00 = {}, acc01 = {}, acc10 = {}, acc11 = {};

    for (int k0 = 0; k0 < K; k0 += 32) {
        *(s16x8*)&As[srow][scol] =
            *(const s16x8*)(A + (long long)(m0 + srow) * lda + k0 + scol);
        *(s16x8*)&Ws[srow][scol] =
            *(const s16x8*)(W + (long long)(n0 + srow) * ldw + k0 + scol);
        __syncthreads();
        s16x8 a0 = *(const s16x8*)&As[wr * 32 + fr][kq];
        s16x8 a1 = *(const s16x8*)&As[wr * 32 + 16 + fr][kq];
        s16x8 b0 = *(const s16x8*)&Ws[wc * 32 + fr][kq];
        s16x8 b1 = *(const s16x8*)&Ws[wc * 32 + 16 + fr][kq];
        acc00 = __builtin_amdgcn_mfma_f32_16x16x32_bf16(a0, b0, acc00, 0, 0, 0);
        acc01 = __builtin_amdgcn_mfma_f32_16x16x32_bf16(a0, b1, acc01, 0, 0, 0);
        acc10 = __builtin_amdgcn_mfma_f32_16x16x32_bf16(a1, b0, acc10, 0, 0, 0);
        acc11 = __builtin_amdgcn_mfma_f32_16x16x32_bf16(a1, b1, acc11, 0, 0, 0);
        __syncthreads();
    }

    int rbase = (lane >> 4) * 4;
#pragma unroll
    for (int p = 0; p < 4; ++p) {
        int mrow0 = wr * 32 + rbase + p;
        int mrow1 = mrow0 + 16;
        int ncol0 = wc * 32 + fr;
        int ncol1 = ncol0 + 16;
        float v00 = acc00[p], v01 = acc01[p], v10 = acc10[p], v11 = acc11[p];
        long long r0 = m0 + mrow0, r1 = m0 + mrow1;
        int c0 = n0 + ncol0, c1 = n0 + ncol1;
        if (add1) {
            v00 += add1[r0 * lda1 + c0]; v01 += add1[r0 * lda1 + c1];
            v10 += add1[r1 * lda1 + c0]; v11 += add1[r1 * lda1 + c1];
        }
        if (add2) {
            v00 += add2[r0 * lda2 + c0]; v01 += add2[r0 * lda2 + c1];
            v10 += add2[r1 * lda2 + c0]; v11 += add2[r1 * lda2 + c1];
        }
        if (Cb) {
            Cb[r0 * ldc + c0] = f2bf(v00); Cb[r0 * ldc + c1] = f2bf(v01);
            Cb[r1 * ldc + c0] = f2bf(v10); Cb[r1 * ldc + c1] = f2bf(v11);
        } else {
            C[r0 * ldc + c0] = v00; C[r0 * ldc + c1] = v01;
            C[r1 * ldc + c0] = v10; C[r1 * ldc + c1] = v11;
        }
    }
}

// --------- transpose head_v: [k*4+b][n*64+d] -> [(b*16+n)*64+d][k] ---------
__global__ __launch_bounds__(256) void transpose_v_kernel(
    const ushort* __restrict__ vin, ushort* __restrict__ vout)
{
    __shared__ __align__(16) ushort T[64][72];
    int bn = blockIdx.y;
    int b = bn >> 4, n = bn & 15;
    int k0 = blockIdx.x * 64;
    int t = threadIdx.x;
    {
        int kr = t >> 2, dp = (t & 3) * 16;
        const ushort* sp = vin + (((long long)(k0 + kr)) * 4 + b) * DM + n * DHD + dp;
        *(s16x8*)&T[kr][dp] = *(const s16x8*)sp;
        *(s16x8*)&T[kr][dp + 8] = *(const s16x8*)(sp + 8);
    }
    __syncthreads();
    {
        int d = t >> 2, kp = (t & 3) * 16;
        ushort vals[16];
#pragma unroll
        for (int q = 0; q < 16; ++q) vals[q] = T[kp + q][d];
        ushort* dp = vout + ((long long)bn * DHD + d) * KL + k0 + kp;
        *(s16x8*)dp = *(const s16x8*)&vals[0];
        *(s16x8*)(dp + 8) = *(const s16x8*)&vals[8];
    }
}

// --------- corr[n,k] = sum_d (rrb[n,d]-rwb[n,d]) * r_head_k[k,n,d] ---------
__global__ __launch_bounds__(256) void corr_kernel(
    const ushort* __restrict__ r_hk, const float* __restrict__ rwb,
    const float* __restrict__ rrb, float* __restrict__ corr)
{
    int n = blockIdx.y;
    int k = blockIdx.x * 4 + (threadIdx.x >> 6);
    int d = threadIdx.x & 63;
    float diff = rrb[n * DHD + d] - rwb[n * DHD + d];
    float v = diff * bf2f(r_hk[(long long)k * DM + n * DHD + d]);
    v = wave_sum64(v);
    if (d == 0) corr[n * RL + k] = v;
}

// ---------------- MFMA flash rel-shift attention (prefetch + BD ring) ------
// grid (8, 64); 256 thr = 4 waves; wave w owns q-rows [w*16, w*16+16).
// RKs/BDs are rings indexed by absolute r & 127; tiles jt>=1 compute only
// the 64 NEW BD columns (window overlap carry).
__global__ __launch_bounds__(256) void attn_mfma_kernel(
    const ushort* __restrict__ hq, const ushort* __restrict__ hk,
    const ushort* __restrict__ hvT, const ushort* __restrict__ rhk,
    const float* __restrict__ corr, ushort* __restrict__ attn_out)
{
    __shared__ __align__(16) ushort Ks[64][72];    // [j][d]
    __shared__ __align__(16) ushort VsT[64][72];   // [d][j]
    __shared__ __align__(16) ushort RKs[128][72];  // ring [r&127][d]
    __shared__ __align__(16) ushort BDs[64][132];  // ring [i_loc][r&127] (corr folded)
    __shared__ __align__(16) ushort Ps[64][72];    // [i_loc][jc]

    int bh = blockIdx.y;
    int b = bh >> 4, n = bh & 15;
    int i0 = blockIdx.x * 64;
    int t = threadIdx.x;
    int lane = t & 63, w = t >> 6;
    int lr16 = lane & 15;
    int lk8 = (lane >> 4) * 8;
    int orow = (lane >> 4) * 4;

    // Q fragments (rows w*16 + lr16) — head_q already includes r_w_bias
    s16x8 qf0, qf1;
    {
        const ushort* qp = hq + (((long long)(i0 + w * 16 + lr16)) * 4 + b) * DM
                              + n * DHD + lk8;
        qf0 = *(const s16x8*)qp;
        qf1 = *(const s16x8*)(qp + 32);
    }

    f32x4 O[4] = {};
    float m_[4], l_[4];
#pragma unroll
    for (int r = 0; r < 4; ++r) { m_[r] = -INFINITY; l_[r] = 0.0f; }

    int nJ = ((i0 + 575) >> 6) + 1;
    if (nJ > 16) nJ = 16;
    int ka0 = 448 - i0;              // >= 0, multiple of 64

    int srow = t >> 2, sdp = (t & 3) * 16;      // K/V/RK-prefetch staging map

    {   // ---- initial stage: K,V tile0 + RK rows [ka0, ka0+128) (always < RL)
        const ushort* kp = hk + (((long long)srow) * 4 + b) * DM + n * DHD + sdp;
        *(s16x8*)&Ks[srow][sdp] = *(const s16x8*)kp;
        *(s16x8*)&Ks[srow][sdp + 8] = *(const s16x8*)(kp + 8);
        const ushort* vp = hvT + ((long long)bh * DHD + srow) * KL + sdp;
        *(s16x8*)&VsT[srow][sdp] = *(const s16x8*)vp;
        *(s16x8*)&VsT[srow][sdp + 8] = *(const s16x8*)(vp + 8);
        int rr = t >> 1, dp2 = (t & 1) * 32;
        int rabs = ka0 + rr;
        const ushort* rp = rhk + (long long)rabs * DM + n * DHD + dp2;
        int phys = rabs & 127;
#pragma unroll
        for (int q = 0; q < 4; ++q)
            *(s16x8*)&RKs[phys][dp2 + q * 8] = *(const s16x8*)(rp + q * 8);
    }
    __syncthreads();

    for (int jt = 0; jt < nJ; ++jt) {
        int j0 = jt * 64;
        int ka = ka0 + j0;
        bool hasNext = (jt + 1) < nJ;

        // ---- issue next-tile global loads into registers (T14) ----
        s16x8 pk0 = {}, pk1 = {}, pv0 = {}, pv1 = {}, pr0 = {}, pr1 = {};
        if (hasNext) {
            int j0n = j0 + 64;
            const ushort* kp = hk + (((long long)(j0n + srow)) * 4 + b) * DM + n * DHD + sdp;
            pk0 = *(const s16x8*)kp;
            pk1 = *(const s16x8*)(kp + 8);
            const ushort* vp = hvT + ((long long)bh * DHD + srow) * KL + j0n + sdp;
            pv0 = *(const s16x8*)vp;
            pv1 = *(const s16x8*)(vp + 8);
            int rnew = ka + 128 + srow;
            if (rnew < RL) {
                const ushort* rp = rhk + (long long)rnew * DM + n * DHD + sdp;
                pr0 = *(const s16x8*)rp;
                pr1 = *(const s16x8*)(rp + 8);
            }
        }

        // ---- AC (8 MFMA) ----
        f32x4 ac[4] = {};
#pragma unroll
        for (int nb = 0; nb < 4; ++nb) {
            s16x8 kb0 = *(const s16x8*)&Ks[nb * 16 + lr16][lk8];
            s16x8 kb1 = *(const s16x8*)&Ks[nb * 16 + lr16][32 + lk8];
            ac[nb] = __builtin_amdgcn_mfma_f32_16x16x32_bf16(qf0, kb0, ac[nb], 0, 0, 0);
            ac[nb] = __builtin_amdgcn_mfma_f32_16x16x32_bf16(qf1, kb1, ac[nb], 0, 0, 0);
        }
        // ---- BD: tile0 computes all 128 cols, later tiles only new 64 ----
        int nb0 = (jt == 0) ? 0 : 4;
        for (int nb = nb0; nb < 8; ++nb) {
            int kk = nb * 16 + lr16;
            int rabs = ka + kk;
            int phys = rabs & 127;
            f32x4 bd = {};
            s16x8 rb0 = *(const s16x8*)&RKs[phys][lk8];
            s16x8 rb1 = *(const s16x8*)&RKs[phys][32 + lk8];
            bd = __builtin_amdgcn_mfma_f32_16x16x32_bf16(qf0, rb0, bd, 0, 0, 0);
            bd = __builtin_amdgcn_mfma_f32_16x16x32_bf16(qf1, rb1, bd, 0, 0, 0);
            float cadd = (rabs < RL) ? corr[n * RL + rabs] : 0.0f;
#pragma unroll
            for (int reg = 0; reg < 4; ++reg)
                BDs[w * 16 + orow + reg][phys] = f2bf(bd[reg] + cadd);
        }
        __syncthreads();

        // ---- rel-shift assembly + online softmax ----
#pragma unroll
        for (int reg = 0; reg < 4; ++reg) {
            int il = w * 16 + orow + reg;
            int i = i0 + il;
            float pvv[4];
            float rowm = -INFINITY;
#pragma unroll
            for (int nb = 0; nb < 4; ++nb) {
                int jc = nb * 16 + lr16;
                int j = j0 + jc;
                float s = -INFINITY;
                if (j <= i + M_LEN) {
                    int phys = (j + 511 - i) & 127;
                    s = (ac[nb][reg] + bf2f(BDs[il][phys])) * ATT_SCALE;
                }
                pvv[nb] = s;
                rowm = fmaxf(rowm, s);
            }
            rowm = fmaxf(rowm, __shfl_xor(rowm, 1));
            rowm = fmaxf(rowm, __shfl_xor(rowm, 2));
            rowm = fmaxf(rowm, __shfl_xor(rowm, 4));
            rowm = fmaxf(rowm, __shfl_xor(rowm, 8));
            float newm = fmaxf(m_[reg], rowm);
            float alpha = __expf(m_[reg] - newm);
            float rs = 0.0f;
#pragma unroll
            for (int nb = 0; nb < 4; ++nb) {
                float p = __expf(pvv[nb] - newm);
                rs += p;
                Ps[il][nb * 16 + lr16] = f2bf(p);
            }
            rs += __shfl_xor(rs, 1);
            rs += __shfl_xor(rs, 2);
            rs += __shfl_xor(rs, 4);
            rs += __shfl_xor(rs, 8);
            l_[reg] = l_[reg] * alpha + rs;
            m_[reg] = newm;
#pragma unroll
            for (int nb = 0; nb < 4; ++nb) O[nb][reg] *= alpha;
        }
        __syncthreads();

        // ---- PV (8 MFMA) ----
#pragma unroll
        for (int kc = 0; kc < 2; ++kc) {
            s16x8 pa = *(const s16x8*)&Ps[w * 16 + lr16][kc * 32 + lk8];
#pragma unroll
            for (int nb = 0; nb < 4; ++nb) {
                s16x8 vb = *(const s16x8*)&VsT[nb * 16 + lr16][kc * 32 + lk8];
                O[nb] = __builtin_amdgcn_mfma_f32_16x16x32_bf16(pa, vb, O[nb], 0, 0, 0);
            }
        }

        if (hasNext) {
            __syncthreads();     // all LDS consumed
            *(s16x8*)&Ks[srow][sdp] = pk0;
            *(s16x8*)&Ks[srow][sdp + 8] = pk1;
            *(s16x8*)&VsT[srow][sdp] = pv0;
            *(s16x8*)&VsT[srow][sdp + 8] = pv1;
            int phys = (ka + 128 + srow) & 127;
            *(s16x8*)&RKs[phys][sdp] = pr0;
            *(s16x8*)&RKs[phys][sdp + 8] = pr1;
            __syncthreads();     // staged for jt+1
        }
    }

    // ---- epilogue ----
#pragma unroll
    for (int reg = 0; reg < 4; ++reg) {
        int il = w * 16 + orow + reg;
        long long i = i0 + il;
        float inv = 1.0f / l_[reg];
#pragma unroll
        for (int nb = 0; nb < 4; ++nb)
            attn_out[(i * 4 + b) * DM + n * DHD + nb * 16 + lr16] = f2bf(O[nb][reg] * inv);
    }
}

extern "C" void kernel_launch(void* const* d_in, const int* in_sizes, int n_in,
                              void* d_out, int out_size, void* d_ws, size_t ws_size,
                              hipStream_t stream) {
    const float* w       = (const float*)d_in[0];
    const float* r       = (const float*)d_in[1];
    const float* rwb     = (const float*)d_in[2];
    const float* rrb     = (const float*)d_in[3];
    const float* mems    = (const float*)d_in[4];
    const float* gamma_q = (const float*)d_in[5];
    const float* beta_q  = (const float*)d_in[6];
    const float* gamma_kv= (const float*)d_in[7];
    const float* beta_kv = (const float*)d_in[8];
    const float* Wq      = (const float*)d_in[9];
    const float* Wiq     = (const float*)d_in[10];
    const float* Wk      = (const float*)d_in[11];
    const float* Wv      = (const float*)d_in[12];
    const float* Wr      = (const float*)d_in[13];
    const float* Wintra  = (const float*)d_in[14];
    const float* Winter  = (const float*)d_in[15];
    float* out = (float*)d_out;
    float* ws = (float*)d_ws;

    float* tmp  = ws;                         // 524,288 f32
    float* corr = tmp + 524288;               // 16,384 f32

    ushort* w_norm_bf  = (ushort*)(corr + 16384);
    ushort* kv_norm_bf = w_norm_bf + 2097152;
    ushort* head_q_bf  = kv_norm_bf + 4194304;   // includes r_w_bias
    ushort* head_k_bf  = head_q_bf + 2097152;
    ushort* head_v_bf  = head_k_bf + 4194304;
    ushort* head_vT_bf = head_v_bf + 4194304;
    ushort* r_hk_bf    = head_vT_bf + 4194304;
    ushort* attn_o_bf  = r_hk_bf + 1048576;
    ushort* r_bf       = attn_o_bf + 2097152;
    ushort* Wk_bf      = r_bf + 1048576;
    ushort* Wv_bf      = Wk_bf + 1048576;
    ushort* Wq_bf      = Wv_bf + 1048576;
    ushort* Wiq_bf     = Wq_bf + 262144;
    ushort* Wr_bf      = Wiq_bf + 262144;
    ushort* Wintra_bf  = Wr_bf + 262144;
    ushort* Winter_bf  = Wintra_bf + 262144;

    group_ln_kernel<<<dim3(Q_LEN * BSZ * NG), 64, 0, stream>>>(w, gamma_q, beta_q, w_norm_bf);
    kv_ln_kernel<<<dim3(KL * BSZ), 256, 0, stream>>>(mems, w, gamma_kv, beta_kv, kv_norm_bf);

    cast8_kernel<<<dim3(4352), 256, 0, stream>>>(
        r, Wk, Wv, Wq, Wiq, Wr, Wintra, Winter,
        r_bf, Wk_bf, Wv_bf, Wq_bf, Wiq_bf, Wr_bf, Wintra_bf, Winter_bf);

    // head_k / head_v -> bf16
    gemm_bf16_nt<<<dim3(16, 64, 1), 256, 0, stream>>>(
        kv_norm_bf, 0, DM, Wk_bf, 0, DM, nullptr, head_k_bf, 0, DM, KL * BSZ, DM, DM,
        nullptr, 0, 0, nullptr, 0, 0);
    gemm_bf16_nt<<<dim3(16, 64, 1), 256, 0, stream>>>(
        kv_norm_bf, 0, DM, Wv_bf, 0, DM, nullptr, head_v_bf, 0, DM, KL * BSZ, DM, DM,
        nullptr, 0, 0, nullptr, 0, 0);
    transpose_v_kernel<<<dim3(16, 64), 256, 0, stream>>>(head_v_bf, head_vT_bf);

    // q_global -> tmp (f32)
    gemm_bf16_nt<<<dim3(4, 32, 1), 256, 0, stream>>>(
        w_norm_bf, 0, DM, Wiq_bf, 0, DM, tmp, nullptr, 0, DGRP, Q_LEN * BSZ, DGRP, DM,
        nullptr, 0, 0, nullptr, 0, 0);
    // head_q = grouped(w_norm*Wq^T) + q_global + rwb  -> bf16
    gemm_bf16_nt<<<dim3(4, 32, 4), 256, 0, stream>>>(
        w_norm_bf, DGRP, DM, Wq_bf, DGRP * DGRP, DGRP, nullptr, head_q_bf, DGRP, DM,
        Q_LEN * BSZ, DGRP, DGRP, tmp, 0, DGRP, rwb, DGRP, 0);
    // r_head_k -> bf16
    gemm_bf16_nt<<<dim3(4, 16, 4), 256, 0, stream>>>(
        r_bf, DGRP, DM, Wr_bf, DGRP * DGRP, DGRP, nullptr, r_hk_bf, DGRP, DM,
        RL, DGRP, DGRP, nullptr, 0, 0, nullptr, 0, 0);

    corr_kernel<<<dim3(RL / 4, NH), 256, 0, stream>>>(r_hk_bf, rwb, rrb, corr);

    attn_mfma_kernel<<<dim3(Q_LEN / 64, BSZ * NH), 256, 0, stream>>>(
        head_q_bf, head_k_bf, head_vT_bf, r_hk_bf, corr, attn_o_bf);

    // inter -> tmp (f32)
    gemm_bf16_nt<<<dim3(4, 32, 1), 256, 0, stream>>>(
        attn_o_bf, 0, DM, Winter_bf, 0, DM, tmp, nullptr, 0, DGRP, Q_LEN * BSZ, DGRP, DM,
        nullptr, 0, 0, nullptr, 0, 0);
    // out = grouped(attn_o*Wintra^T) + inter + w
    gemm_bf16_nt<<<dim3(4, 32, 4), 256, 0, stream>>>(
        attn_o_bf, DGRP, DM, Wintra_bf, DGRP * DGRP, DGRP, out, nullptr, DGRP, DM,
        Q_LEN * BSZ, DGRP, DGRP, tmp, 0, DGRP, w, DGRP, DM);
}

// Round 9
// 193.290 us; speedup vs baseline: 4.3290x; 1.0608x over previous
//
#include <hip/hip_runtime.h>
#include <math.h>

#define Q_LEN 512
#define M_LEN 512
#define KL    1024
#define BSZ   4
#define DM    1024
#define NH    16
#define DHD   64
#define NG    4
#define DGRP  256
#define RL    1024
#define LN_EPS 1e-6f
#define ATT_SCALE 0.125f

typedef short s16x8 __attribute__((ext_vector_type(8)));
typedef float f32x4 __attribute__((ext_vector_type(4)));

__device__ __forceinline__ float wave_sum64(float v) {
#pragma unroll
    for (int off = 32; off > 0; off >>= 1) v += __shfl_xor(v, off);
    return v;
}

__device__ __forceinline__ ushort f2bf(float f) {
    unsigned u = __float_as_uint(f);
    unsigned r = (u + 0x7fffu + ((u >> 16) & 1u)) >> 16;   // RNE
    return (ushort)r;
}
__device__ __forceinline__ float bf2f(ushort u) {
    return __uint_as_float(((unsigned)u) << 16);
}

// ---------------- fused f32 -> bf16 cast of all 8 weight arrays ------------
__global__ __launch_bounds__(256) void cast8_kernel(
    const float* p0, const float* p1, const float* p2, const float* p3,
    const float* p4, const float* p5, const float* p6, const float* p7,
    ushort* d0, ushort* d1, ushort* d2, ushort* d3,
    ushort* d4, ushort* d5, ushort* d6, ushort* d7)
{
    int bid = blockIdx.x;
    const float* s; ushort* d; int off;
    if      (bid < 1024) { s = p0; d = d0; off = bid; }
    else if (bid < 2048) { s = p1; d = d1; off = bid - 1024; }
    else if (bid < 3072) { s = p2; d = d2; off = bid - 2048; }
    else if (bid < 3328) { s = p3; d = d3; off = bid - 3072; }
    else if (bid < 3584) { s = p4; d = d4; off = bid - 3328; }
    else if (bid < 3840) { s = p5; d = d5; off = bid - 3584; }
    else if (bid < 4096) { s = p6; d = d6; off = bid - 3840; }
    else                 { s = p7; d = d7; off = bid - 4096; }
    int i = off * 1024 + threadIdx.x * 4;
    float4 v = *(const float4*)(s + i);
    ushort4 o;
    o.x = f2bf(v.x); o.y = f2bf(v.y); o.z = f2bf(v.z); o.w = f2bf(v.w);
    *(ushort4*)(d + i) = o;
}

// ---------------- group LayerNorm for w (G=4 groups of 256) -> bf16 --------
__global__ __launch_bounds__(64) void group_ln_kernel(
    const float* __restrict__ w, const float* __restrict__ gamma,
    const float* __restrict__ beta, ushort* __restrict__ out)
{
    int bid = blockIdx.x;              // (q*BSZ + b)*NG + g
    int g = bid & (NG - 1);
    long long row = bid >> 2;
    int t = threadIdx.x;
    long long base = row * DM + g * DGRP + t * 4;
    float4 x = *(const float4*)(w + base);
    float mean = wave_sum64(x.x + x.y + x.z + x.w) * (1.0f / 256.0f);
    float dx = x.x - mean, dy = x.y - mean, dz = x.z - mean, dw = x.w - mean;
    float ss = wave_sum64(dx * dx + dy * dy + dz * dz + dw * dw);
    float inv = 1.0f / (sqrtf(ss * (1.0f / 255.0f)) + LN_EPS);   // ddof=1
    int db = g * DGRP + t * 4;
    float4 ga = *(const float4*)(gamma + db);
    float4 be = *(const float4*)(beta + db);
    ushort4 o;
    o.x = f2bf(ga.x * (dx * inv) + be.x);
    o.y = f2bf(ga.y * (dy * inv) + be.y);
    o.z = f2bf(ga.z * (dz * inv) + be.z);
    o.w = f2bf(ga.w * (dw * inv) + be.w);
    *(ushort4*)(out + base) = o;
}

// ---------------- full LayerNorm for kv = concat(mems, w) -> bf16 ----------
__global__ __launch_bounds__(256) void kv_ln_kernel(
    const float* __restrict__ mems, const float* __restrict__ w,
    const float* __restrict__ gamma, const float* __restrict__ beta,
    ushort* __restrict__ out)
{
    int row = blockIdx.x;              // k*BSZ + b
    int k = row >> 2, b = row & 3;
    const float* src = (k < M_LEN) ? (mems + ((long long)k * BSZ + b) * DM)
                                   : (w + ((long long)(k - M_LEN) * BSZ + b) * DM);
    int t = threadIdx.x;
    float4 x = *(const float4*)(src + t * 4);
    __shared__ float red[4];
    float s = wave_sum64(x.x + x.y + x.z + x.w);
    int wv = t >> 6, ln = t & 63;
    if (ln == 0) red[wv] = s;
    __syncthreads();
    float mean = (red[0] + red[1] + red[2] + red[3]) * (1.0f / 1024.0f);
    float dx = x.x - mean, dy = x.y - mean, dz = x.z - mean, dw = x.w - mean;
    float ss = wave_sum64(dx * dx + dy * dy + dz * dz + dw * dw);
    __syncthreads();
    if (ln == 0) red[wv] = ss;
    __syncthreads();
    float var = (red[0] + red[1] + red[2] + red[3]) * (1.0f / 1023.0f);
    float inv = 1.0f / (sqrtf(var) + LN_EPS);
    int db = t * 4;
    float4 ga = *(const float4*)(gamma + db);
    float4 be = *(const float4*)(beta + db);
    ushort4 o;
    o.x = f2bf(ga.x * (dx * inv) + be.x);
    o.y = f2bf(ga.y * (dy * inv) + be.y);
    o.z = f2bf(ga.z * (dz * inv) + be.z);
    o.w = f2bf(ga.w * (dw * inv) + be.w);
    *(ushort4*)(out + (long long)row * DM + db) = o;
}

// ------ bf16 MFMA GEMM  C = A[M,K] * W[N,K]^T  (+add1 +add2), f32 or bf16 out
__global__ __launch_bounds__(256) void gemm_bf16_nt(
    const ushort* __restrict__ A, long long aZ, int lda,
    const ushort* __restrict__ W, long long wZ, int ldw,
    float* __restrict__ C, ushort* __restrict__ Cb, long long cZ, int ldc,
    int M, int N, int K,
    const float* __restrict__ add1, long long a1Z, int lda1,
    const float* __restrict__ add2, long long a2Z, int lda2)
{
    int z = blockIdx.z;
    A += (long long)z * aZ;
    W += (long long)z * wZ;
    if (C)  C += (long long)z * cZ;
    if (Cb) Cb += (long long)z * cZ;
    if (add1) add1 += (long long)z * a1Z;
    if (add2) add2 += (long long)z * a2Z;
    int m0 = blockIdx.y * 64, n0 = blockIdx.x * 64;
    int t = threadIdx.x;
    int lane = t & 63, wid = t >> 6;
    int wr = wid >> 1, wc = wid & 1;
    int srow = t >> 2, scol = (t & 3) * 8;
    int fr = lane & 15, kq = (lane >> 4) * 8;

    __shared__ __align__(16) ushort As[64][40];
    __shared__ __align__(16) ushort Ws[64][40];

    f32x4 acc00 = {}, acc01 = {}, acc10 = {}, acc11 = {};

    for (int k0 = 0; k0 < K; k0 += 32) {
        *(s16x8*)&As[srow][scol] =
            *(const s16x8*)(A + (long long)(m0 + srow) * lda + k0 + scol);
        *(s16x8*)&Ws[srow][scol] =
            *(const s16x8*)(W + (long long)(n0 + srow) * ldw + k0 + scol);
        __syncthreads();
        s16x8 a0 = *(const s16x8*)&As[wr * 32 + fr][kq];
        s16x8 a1 = *(const s16x8*)&As[wr * 32 + 16 + fr][kq];
        s16x8 b0 = *(const s16x8*)&Ws[wc * 32 + fr][kq];
        s16x8 b1 = *(const s16x8*)&Ws[wc * 32 + 16 + fr][kq];
        acc00 = __builtin_amdgcn_mfma_f32_16x16x32_bf16(a0, b0, acc00, 0, 0, 0);
        acc01 = __builtin_amdgcn_mfma_f32_16x16x32_bf16(a0, b1, acc01, 0, 0, 0);
        acc10 = __builtin_amdgcn_mfma_f32_16x16x32_bf16(a1, b0, acc10, 0, 0, 0);
        acc11 = __builtin_amdgcn_mfma_f32_16x16x32_bf16(a1, b1, acc11, 0, 0, 0);
        __syncthreads();
    }

    int rbase = (lane >> 4) * 4;
#pragma unroll
    for (int p = 0; p < 4; ++p) {
        int mrow0 = wr * 32 + rbase + p;
        int mrow1 = mrow0 + 16;
        int ncol0 = wc * 32 + fr;
        int ncol1 = ncol0 + 16;
        float v00 = acc00[p], v01 = acc01[p], v10 = acc10[p], v11 = acc11[p];
        long long r0 = m0 + mrow0, r1 = m0 + mrow1;
        int c0 = n0 + ncol0, c1 = n0 + ncol1;
        if (add1) {
            v00 += add1[r0 * lda1 + c0]; v01 += add1[r0 * lda1 + c1];
            v10 += add1[r1 * lda1 + c0]; v11 += add1[r1 * lda1 + c1];
        }
        if (add2) {
            v00 += add2[r0 * lda2 + c0]; v01 += add2[r0 * lda2 + c1];
            v10 += add2[r1 * lda2 + c0]; v11 += add2[r1 * lda2 + c1];
        }
        if (Cb) {
            Cb[r0 * ldc + c0] = f2bf(v00); Cb[r0 * ldc + c1] = f2bf(v01);
            Cb[r1 * ldc + c0] = f2bf(v10); Cb[r1 * ldc + c1] = f2bf(v11);
        } else {
            C[r0 * ldc + c0] = v00; C[r0 * ldc + c1] = v01;
            C[r1 * ldc + c0] = v10; C[r1 * ldc + c1] = v11;
        }
    }
}

// --------- transpose head_v: [k*4+b][n*64+d] -> [(b*16+n)*64+d][k] ---------
__global__ __launch_bounds__(256) void transpose_v_kernel(
    const ushort* __restrict__ vin, ushort* __restrict__ vout)
{
    __shared__ __align__(16) ushort T[64][72];
    int bn = blockIdx.y;
    int b = bn >> 4, n = bn & 15;
    int k0 = blockIdx.x * 64;
    int t = threadIdx.x;
    {
        int kr = t >> 2, dp = (t & 3) * 16;
        const ushort* sp = vin + (((long long)(k0 + kr)) * 4 + b) * DM + n * DHD + dp;
        *(s16x8*)&T[kr][dp] = *(const s16x8*)sp;
        *(s16x8*)&T[kr][dp + 8] = *(const s16x8*)(sp + 8);
    }
    __syncthreads();
    {
        int d = t >> 2, kp = (t & 3) * 16;
        ushort vals[16];
#pragma unroll
        for (int q = 0; q < 16; ++q) vals[q] = T[kp + q][d];
        ushort* dp = vout + ((long long)bn * DHD + d) * KL + k0 + kp;
        *(s16x8*)dp = *(const s16x8*)&vals[0];
        *(s16x8*)(dp + 8) = *(const s16x8*)&vals[8];
    }
}

// --------- corr[n,k] = sum_d (rrb[n,d]-rwb[n,d]) * r_head_k[k,n,d] ---------
__global__ __launch_bounds__(256) void corr_kernel(
    const ushort* __restrict__ r_hk, const float* __restrict__ rwb,
    const float* __restrict__ rrb, float* __restrict__ corr)
{
    int n = blockIdx.y;
    int k = blockIdx.x * 4 + (threadIdx.x >> 6);
    int d = threadIdx.x & 63;
    float diff = rrb[n * DHD + d] - rwb[n * DHD + d];
    float v = diff * bf2f(r_hk[(long long)k * DM + n * DHD + d]);
    v = wave_sum64(v);
    if (d == 0) corr[n * RL + k] = v;
}

// ---------------- MFMA flash rel-shift attention ----------------
// grid (8, 64); 4 waves; wave w owns q-rows [w*16, w*16+16).
// K/V double-buffered; RKs 128-row ring; BDs/Ps wave-private (no barrier);
// ONE __syncthreads() per tile (tile 0: two). LDS = 78 KB -> 2 blocks/CU.
__global__ __launch_bounds__(256) void attn_mfma_kernel(
    const ushort* __restrict__ hq, const ushort* __restrict__ hk,
    const ushort* __restrict__ hvT, const ushort* __restrict__ rhk,
    const float* __restrict__ corr, ushort* __restrict__ attn_out)
{
    __shared__ __align__(16) ushort Ks[2][64][72];   // [buf][j][d]
    __shared__ __align__(16) ushort VsT[2][64][72];  // [buf][d][j]
    __shared__ __align__(16) ushort RKs[128][72];    // ring [r&127][d]
    __shared__ __align__(16) ushort BDs[64][128];    // wave-private rows; XOR-swz
    __shared__ __align__(16) ushort Ps[64][64];      // wave-private rows; XOR-swz

    int bh = blockIdx.y;
    int b = bh >> 4, n = bh & 15;
    int i0 = blockIdx.x * 64;
    int t = threadIdx.x;
    int lane = t & 63, w = t >> 6;
    int lr16 = lane & 15;
    int lk8 = (lane >> 4) * 8;
    int orow = (lane >> 4) * 4;
    int swzBD = ((lane >> 4) & 3) << 4;   // == ((il>>2)&3)<<4 for this lane's rows

    // Q fragments (rows w*16 + lr16) — head_q already includes r_w_bias
    s16x8 qf0, qf1;
    {
        const ushort* qp = hq + (((long long)(i0 + w * 16 + lr16)) * 4 + b) * DM
                              + n * DHD + lk8;
        qf0 = *(const s16x8*)qp;
        qf1 = *(const s16x8*)(qp + 32);
    }

    f32x4 O[4] = {};
    float m_[4], l_[4];
#pragma unroll
    for (int r = 0; r < 4; ++r) { m_[r] = -INFINITY; l_[r] = 0.0f; }

    int nJ = ((i0 + 575) >> 6) + 1;
    if (nJ > 16) nJ = 16;
    int ka0 = 448 - i0;              // >= 0, multiple of 64

    int srow = t >> 2, sdp = (t & 3) * 16;

    {   // ---- prologue: K0,V0 -> buf0; RK rows [ka0, ka0+128) -> ring ----
        const ushort* kp = hk + (((long long)srow) * 4 + b) * DM + n * DHD + sdp;
        *(s16x8*)&Ks[0][srow][sdp] = *(const s16x8*)kp;
        *(s16x8*)&Ks[0][srow][sdp + 8] = *(const s16x8*)(kp + 8);
        const ushort* vp = hvT + ((long long)bh * DHD + srow) * KL + sdp;
        *(s16x8*)&VsT[0][srow][sdp] = *(const s16x8*)vp;
        *(s16x8*)&VsT[0][srow][sdp + 8] = *(const s16x8*)(vp + 8);
        int rr = t >> 1, dp2 = (t & 1) * 32;
        int rabs = ka0 + rr;                         // always < RL
        const ushort* rp = rhk + (long long)rabs * DM + n * DHD + dp2;
        int phys = rabs & 127;
#pragma unroll
        for (int q = 0; q < 4; ++q)
            *(s16x8*)&RKs[phys][dp2 + q * 8] = *(const s16x8*)(rp + q * 8);
    }
    __syncthreads();

    int cur = 0;
    for (int jt = 0; jt < nJ; ++jt) {
        int j0 = jt * 64;
        int ka = ka0 + j0;
        bool hasNext = (jt + 1) < nJ;

        // ---- issue next-tile global loads into registers ----
        s16x8 pk0 = {}, pk1 = {}, pv0 = {}, pv1 = {}, pr0 = {}, pr1 = {};
        if (hasNext) {
            int j0n = j0 + 64;
            const ushort* kp = hk + (((long long)(j0n + srow)) * 4 + b) * DM + n * DHD + sdp;
            pk0 = *(const s16x8*)kp;
            pk1 = *(const s16x8*)(kp + 8);
            const ushort* vp = hvT + ((long long)bh * DHD + srow) * KL + j0n + sdp;
            pv0 = *(const s16x8*)vp;
            pv1 = *(const s16x8*)(vp + 8);
            int rnew = ka + 128 + srow;
            if (rnew < RL) {
                const ushort* rp = rhk + (long long)rnew * DM + n * DHD + sdp;
                pr0 = *(const s16x8*)rp;
                pr1 = *(const s16x8*)(rp + 8);
            }
        }

        // ---- AC (8 MFMA) on Ks[cur] ----
        f32x4 ac[4] = {};
#pragma unroll
        for (int nb = 0; nb < 4; ++nb) {
            s16x8 kb0 = *(const s16x8*)&Ks[cur][nb * 16 + lr16][lk8];
            s16x8 kb1 = *(const s16x8*)&Ks[cur][nb * 16 + lr16][32 + lk8];
            ac[nb] = __builtin_amdgcn_mfma_f32_16x16x32_bf16(qf0, kb0, ac[nb], 0, 0, 0);
            ac[nb] = __builtin_amdgcn_mfma_f32_16x16x32_bf16(qf1, kb1, ac[nb], 0, 0, 0);
        }
        // ---- BD: tile0 all 128 cols, later tiles only new 64 ----
        int nb0 = (jt == 0) ? 0 : 4;
        for (int nb = nb0; nb < 8; ++nb) {
            int kk = nb * 16 + lr16;
            int rabs = ka + kk;
            int phys = rabs & 127;
            f32x4 bd = {};
            s16x8 rb0 = *(const s16x8*)&RKs[phys][lk8];
            s16x8 rb1 = *(const s16x8*)&RKs[phys][32 + lk8];
            bd = __builtin_amdgcn_mfma_f32_16x16x32_bf16(qf0, rb0, bd, 0, 0, 0);
            bd = __builtin_amdgcn_mfma_f32_16x16x32_bf16(qf1, rb1, bd, 0, 0, 0);
            float cadd = (rabs < RL) ? corr[n * RL + rabs] : 0.0f;
            int colw = phys ^ swzBD;
#pragma unroll
            for (int reg = 0; reg < 4; ++reg)
                BDs[w * 16 + orow + reg][colw] = f2bf(bd[reg] + cadd);
        }
        // tile 0: its stage-writes below hit ring slots its BD just read (cross-wave WAR)
        if (jt == 0) __syncthreads();

        // ---- rel-shift assembly + online softmax (wave-private BDs/Ps) ----
#pragma unroll
        for (int reg = 0; reg < 4; ++reg) {
            int il = w * 16 + orow + reg;
            int i = i0 + il;
            float pvv[4];
            float rowm = -INFINITY;
#pragma unroll
            for (int nb = 0; nb < 4; ++nb) {
                int jc = nb * 16 + lr16;
                int j = j0 + jc;
                float s = -INFINITY;
                if (j <= i + M_LEN) {
                    int phys = (j + 511 - i) & 127;
                    s = (ac[nb][reg] + bf2f(BDs[il][phys ^ swzBD])) * ATT_SCALE;
                }
                pvv[nb] = s;
                rowm = fmaxf(rowm, s);
            }
            rowm = fmaxf(rowm, __shfl_xor(rowm, 1));
            rowm = fmaxf(rowm, __shfl_xor(rowm, 2));
            rowm = fmaxf(rowm, __shfl_xor(rowm, 4));
            rowm = fmaxf(rowm, __shfl_xor(rowm, 8));
            float newm = fmaxf(m_[reg], rowm);
            float alpha = __expf(m_[reg] - newm);
            float rs = 0.0f;
#pragma unroll
            for (int nb = 0; nb < 4; ++nb) {
                float p = __expf(pvv[nb] - newm);
                rs += p;
                int jc = nb * 16 + lr16;
                int colp = (((jc >> 3) ^ (il & 7)) << 3) | (jc & 7);
                Ps[il][colp] = f2bf(p);
            }
            rs += __shfl_xor(rs, 1);
            rs += __shfl_xor(rs, 2);
            rs += __shfl_xor(rs, 4);
            rs += __shfl_xor(rs, 8);
            l_[reg] = l_[reg] * alpha + rs;
            m_[reg] = newm;
#pragma unroll
            for (int nb = 0; nb < 4; ++nb) O[nb][reg] *= alpha;
        }

        // ---- PV (8 MFMA) on VsT[cur]; Ps rows are wave-private ----
        {
            int prow = w * 16 + lr16;
            int rh = prow & 7;
#pragma unroll
            for (int kc = 0; kc < 2; ++kc) {
                int blk = kc * 4 + (lane >> 4);
                s16x8 pa = *(const s16x8*)&Ps[prow][(blk ^ rh) << 3];
#pragma unroll
                for (int nb = 0; nb < 4; ++nb) {
                    s16x8 vb = *(const s16x8*)&VsT[cur][nb * 16 + lr16][kc * 32 + lk8];
                    O[nb] = __builtin_amdgcn_mfma_f32_16x16x32_bf16(pa, vb, O[nb], 0, 0, 0);
                }
            }
        }

        // ---- stage prefetched regs -> other buffers / ring ----
        if (hasNext) {
            *(s16x8*)&Ks[cur ^ 1][srow][sdp] = pk0;
            *(s16x8*)&Ks[cur ^ 1][srow][sdp + 8] = pk1;
            *(s16x8*)&VsT[cur ^ 1][srow][sdp] = pv0;
            *(s16x8*)&VsT[cur ^ 1][srow][sdp + 8] = pv1;
            int phys = (ka + 128 + srow) & 127;
            *(s16x8*)&RKs[phys][sdp] = pr0;
            *(s16x8*)&RKs[phys][sdp + 8] = pr1;
        }
        __syncthreads();        // the ONE barrier: orders all cross-wave deps
        cur ^= 1;
    }

    // ---- epilogue ----
#pragma unroll
    for (int reg = 0; reg < 4; ++reg) {
        int il = w * 16 + orow + reg;
        long long i = i0 + il;
        float inv = 1.0f / l_[reg];
#pragma unroll
        for (int nb = 0; nb < 4; ++nb)
            attn_out[(i * 4 + b) * DM + n * DHD + nb * 16 + lr16] = f2bf(O[nb][reg] * inv);
    }
}

extern "C" void kernel_launch(void* const* d_in, const int* in_sizes, int n_in,
                              void* d_out, int out_size, void* d_ws, size_t ws_size,
                              hipStream_t stream) {
    const float* w       = (const float*)d_in[0];
    const float* r       = (const float*)d_in[1];
    const float* rwb     = (const float*)d_in[2];
    const float* rrb     = (const float*)d_in[3];
    const float* mems    = (const float*)d_in[4];
    const float* gamma_q = (const float*)d_in[5];
    const float* beta_q  = (const float*)d_in[6];
    const float* gamma_kv= (const float*)d_in[7];
    const float* beta_kv = (const float*)d_in[8];
    const float* Wq      = (const float*)d_in[9];
    const float* Wiq     = (const float*)d_in[10];
    const float* Wk      = (const float*)d_in[11];
    const float* Wv      = (const float*)d_in[12];
    const float* Wr      = (const float*)d_in[13];
    const float* Wintra  = (const float*)d_in[14];
    const float* Winter  = (const float*)d_in[15];
    float* out = (float*)d_out;
    float* ws = (float*)d_ws;

    float* tmp  = ws;                         // 524,288 f32
    float* corr = tmp + 524288;               // 16,384 f32

    ushort* w_norm_bf  = (ushort*)(corr + 16384);
    ushort* kv_norm_bf = w_norm_bf + 2097152;
    ushort* head_q_bf  = kv_norm_bf + 4194304;   // includes r_w_bias
    ushort* head_k_bf  = head_q_bf + 2097152;
    ushort* head_v_bf  = head_k_bf + 4194304;    // contiguous after head_k
    ushort* head_vT_bf = head_v_bf + 4194304;
    ushort* r_hk_bf    = head_vT_bf + 4194304;
    ushort* attn_o_bf  = r_hk_bf + 1048576;
    ushort* r_bf       = attn_o_bf + 2097152;
    ushort* Wk_bf      = r_bf + 1048576;
    ushort* Wv_bf      = Wk_bf + 1048576;        // contiguous after Wk
    ushort* Wq_bf      = Wv_bf + 1048576;
    ushort* Wiq_bf     = Wq_bf + 262144;
    ushort* Wr_bf      = Wiq_bf + 262144;
    ushort* Wintra_bf  = Wr_bf + 262144;
    ushort* Winter_bf  = Wintra_bf + 262144;

    group_ln_kernel<<<dim3(Q_LEN * BSZ * NG), 64, 0, stream>>>(w, gamma_q, beta_q, w_norm_bf);
    kv_ln_kernel<<<dim3(KL * BSZ), 256, 0, stream>>>(mems, w, gamma_kv, beta_kv, kv_norm_bf);

    cast8_kernel<<<dim3(4352), 256, 0, stream>>>(
        r, Wk, Wv, Wq, Wiq, Wr, Wintra, Winter,
        r_bf, Wk_bf, Wv_bf, Wq_bf, Wiq_bf, Wr_bf, Wintra_bf, Winter_bf);

    // head_k & head_v in ONE dispatch (z: weight stride 1M, out stride 4M elems)
    gemm_bf16_nt<<<dim3(16, 64, 2), 256, 0, stream>>>(
        kv_norm_bf, 0, DM, Wk_bf, 1048576, DM, nullptr, head_k_bf, 4194304, DM,
        KL * BSZ, DM, DM, nullptr, 0, 0, nullptr, 0, 0);
    transpose_v_kernel<<<dim3(16, 64), 256, 0, stream>>>(head_v_bf, head_vT_bf);

    // q_global -> tmp (f32)
    gemm_bf16_nt<<<dim3(4, 32, 1), 256, 0, stream>>>(
        w_norm_bf, 0, DM, Wiq_bf, 0, DM, tmp, nullptr, 0, DGRP, Q_LEN * BSZ, DGRP, DM,
        nullptr, 0, 0, nullptr, 0, 0);
    // head_q = grouped(w_norm*Wq^T) + q_global + rwb  -> bf16
    gemm_bf16_nt<<<dim3(4, 32, 4), 256, 0, stream>>>(
        w_norm_bf, DGRP, DM, Wq_bf, DGRP * DGRP, DGRP, nullptr, head_q_bf, DGRP, DM,
        Q_LEN * BSZ, DGRP, DGRP, tmp, 0, DGRP, rwb, DGRP, 0);
    // r_head_k -> bf16
    gemm_bf16_nt<<<dim3(4, 16, 4), 256, 0, stream>>>(
        r_bf, DGRP, DM, Wr_bf, DGRP * DGRP, DGRP, nullptr, r_hk_bf, DGRP, DM,
        RL, DGRP, DGRP, nullptr, 0, 0, nullptr, 0, 0);

    corr_kernel<<<dim3(RL / 4, NH), 256, 0, stream>>>(r_hk_bf, rwb, rrb, corr);

    attn_mfma_kernel<<<dim3(Q_LEN / 64, BSZ * NH), 256, 0, stream>>>(
        head_q_bf, head_k_bf, head_vT_bf, r_hk_bf, corr, attn_o_bf);

    // inter -> tmp (f32)
    gemm_bf16_nt<<<dim3(4, 32, 1), 256, 0, stream>>>(
        attn_o_bf, 0, DM, Winter_bf, 0, DM, tmp, nullptr, 0, DGRP, Q_LEN * BSZ, DGRP, DM,
        nullptr, 0, 0, nullptr, 0, 0);
    // out = grouped(attn_o*Wintra^T) + inter + w
    gemm_bf16_nt<<<dim3(4, 32, 4), 256, 0, stream>>>(
        attn_o_bf, DGRP, DM, Wintra_bf, DGRP * DGRP, DGRP, out, nullptr, DGRP, DM,
        Q_LEN * BSZ, DGRP, DGRP, tmp, 0, DGRP, w, DGRP, DM);
}

// Round 10
// 174.766 us; speedup vs baseline: 4.7878x; 1.1060x over previous
//
#include <hip/hip_runtime.h>
#include <math.h>

#define Q_LEN 512
#define M_LEN 512
#define KL    1024
#define BSZ   4
#define DM    1024
#define NH    16
#define DHD   64
#define NG    4
#define DGRP  256
#define RL    1024
#define LN_EPS 1e-6f
#define ATT_SCALE 0.125f

typedef short s16x8 __attribute__((ext_vector_type(8)));
typedef float f32x4 __attribute__((ext_vector_type(4)));

__device__ __forceinline__ float wave_sum64(float v) {
#pragma unroll
    for (int off = 32; off > 0; off >>= 1) v += __shfl_xor(v, off);
    return v;
}

__device__ __forceinline__ ushort f2bf(float f) {
    unsigned u = __float_as_uint(f);
    unsigned r = (u + 0x7fffu + ((u >> 16) & 1u)) >> 16;   // RNE
    return (ushort)r;
}
__device__ __forceinline__ float bf2f(ushort u) {
    return __uint_as_float(((unsigned)u) << 16);
}

// ---------------- fused f32 -> bf16 cast of all 8 weight arrays ------------
__global__ __launch_bounds__(256) void cast8_kernel(
    const float* p0, const float* p1, const float* p2, const float* p3,
    const float* p4, const float* p5, const float* p6, const float* p7,
    ushort* d0, ushort* d1, ushort* d2, ushort* d3,
    ushort* d4, ushort* d5, ushort* d6, ushort* d7)
{
    int bid = blockIdx.x;
    const float* s; ushort* d; int off;
    if      (bid < 1024) { s = p0; d = d0; off = bid; }
    else if (bid < 2048) { s = p1; d = d1; off = bid - 1024; }
    else if (bid < 3072) { s = p2; d = d2; off = bid - 2048; }
    else if (bid < 3328) { s = p3; d = d3; off = bid - 3072; }
    else if (bid < 3584) { s = p4; d = d4; off = bid - 3328; }
    else if (bid < 3840) { s = p5; d = d5; off = bid - 3584; }
    else if (bid < 4096) { s = p6; d = d6; off = bid - 3840; }
    else                 { s = p7; d = d7; off = bid - 4096; }
    int i = off * 1024 + threadIdx.x * 4;
    float4 v = *(const float4*)(s + i);
    ushort4 o;
    o.x = f2bf(v.x); o.y = f2bf(v.y); o.z = f2bf(v.z); o.w = f2bf(v.w);
    *(ushort4*)(d + i) = o;
}

// ---------------- group LayerNorm for w (G=4 groups of 256) -> bf16 --------
__global__ __launch_bounds__(64) void group_ln_kernel(
    const float* __restrict__ w, const float* __restrict__ gamma,
    const float* __restrict__ beta, ushort* __restrict__ out)
{
    int bid = blockIdx.x;              // (q*BSZ + b)*NG + g
    int g = bid & (NG - 1);
    long long row = bid >> 2;
    int t = threadIdx.x;
    long long base = row * DM + g * DGRP + t * 4;
    float4 x = *(const float4*)(w + base);
    float mean = wave_sum64(x.x + x.y + x.z + x.w) * (1.0f / 256.0f);
    float dx = x.x - mean, dy = x.y - mean, dz = x.z - mean, dw = x.w - mean;
    float ss = wave_sum64(dx * dx + dy * dy + dz * dz + dw * dw);
    float inv = 1.0f / (sqrtf(ss * (1.0f / 255.0f)) + LN_EPS);   // ddof=1
    int db = g * DGRP + t * 4;
    float4 ga = *(const float4*)(gamma + db);
    float4 be = *(const float4*)(beta + db);
    ushort4 o;
    o.x = f2bf(ga.x * (dx * inv) + be.x);
    o.y = f2bf(ga.y * (dy * inv) + be.y);
    o.z = f2bf(ga.z * (dz * inv) + be.z);
    o.w = f2bf(ga.w * (dw * inv) + be.w);
    *(ushort4*)(out + base) = o;
}

// ---------------- full LayerNorm for kv = concat(mems, w) -> bf16 ----------
__global__ __launch_bounds__(256) void kv_ln_kernel(
    const float* __restrict__ mems, const float* __restrict__ w,
    const float* __restrict__ gamma, const float* __restrict__ beta,
    ushort* __restrict__ out)
{
    int row = blockIdx.x;              // k*BSZ + b
    int k = row >> 2, b = row & 3;
    const float* src = (k < M_LEN) ? (mems + ((long long)k * BSZ + b) * DM)
                                   : (w + ((long long)(k - M_LEN) * BSZ + b) * DM);
    int t = threadIdx.x;
    float4 x = *(const float4*)(src + t * 4);
    __shared__ float red[4];
    float s = wave_sum64(x.x + x.y + x.z + x.w);
    int wv = t >> 6, ln = t & 63;
    if (ln == 0) red[wv] = s;
    __syncthreads();
    float mean = (red[0] + red[1] + red[2] + red[3]) * (1.0f / 1024.0f);
    float dx = x.x - mean, dy = x.y - mean, dz = x.z - mean, dw = x.w - mean;
    float ss = wave_sum64(dx * dx + dy * dy + dz * dz + dw * dw);
    __syncthreads();
    if (ln == 0) red[wv] = ss;
    __syncthreads();
    float var = (red[0] + red[1] + red[2] + red[3]) * (1.0f / 1023.0f);
    float inv = 1.0f / (sqrtf(var) + LN_EPS);
    int db = t * 4;
    float4 ga = *(const float4*)(gamma + db);
    float4 be = *(const float4*)(beta + db);
    ushort4 o;
    o.x = f2bf(ga.x * (dx * inv) + be.x);
    o.y = f2bf(ga.y * (dy * inv) + be.y);
    o.z = f2bf(ga.z * (dz * inv) + be.z);
    o.w = f2bf(ga.w * (dw * inv) + be.w);
    *(ushort4*)(out + (long long)row * DM + db) = o;
}

// ------ bf16 MFMA GEMM  C = A[M,K] * W[N,K]^T  (+add1 +add2), f32 or bf16 out
// BK=64 staging + register prefetch: next tile's loads issue before compute.
// M,N multiples of 64; K multiple of 64.
__global__ __launch_bounds__(256) void gemm_bf16_nt(
    const ushort* __restrict__ A, long long aZ, int lda,
    const ushort* __restrict__ W, long long wZ, int ldw,
    float* __restrict__ C, ushort* __restrict__ Cb, long long cZ, int ldc,
    int M, int N, int K,
    const float* __restrict__ add1, long long a1Z, int lda1,
    const float* __restrict__ add2, long long a2Z, int lda2)
{
    int z = blockIdx.z;
    A += (long long)z * aZ;
    W += (long long)z * wZ;
    if (C)  C += (long long)z * cZ;
    if (Cb) Cb += (long long)z * cZ;
    if (add1) add1 += (long long)z * a1Z;
    if (add2) add2 += (long long)z * a2Z;
    int m0 = blockIdx.y * 64, n0 = blockIdx.x * 64;
    int t = threadIdx.x;
    int lane = t & 63, wid = t >> 6;
    int wr = wid >> 1, wc = wid & 1;
    int srow = t >> 2, scol = (t & 3) * 16;   // 32B per thread per matrix
    int fr = lane & 15, kq = (lane >> 4) * 8;

    __shared__ __align__(16) ushort As[64][72];   // 2-way banks (free)
    __shared__ __align__(16) ushort Ws[64][72];

    f32x4 acc00 = {}, acc01 = {}, acc10 = {}, acc11 = {};

    const ushort* Arow = A + (long long)(m0 + srow) * lda + scol;
    const ushort* Wrow = W + (long long)(n0 + srow) * ldw + scol;

    // prologue: stage tile k0=0
    s16x8 ra0 = *(const s16x8*)Arow;
    s16x8 ra1 = *(const s16x8*)(Arow + 8);
    s16x8 rw0 = *(const s16x8*)Wrow;
    s16x8 rw1 = *(const s16x8*)(Wrow + 8);
    *(s16x8*)&As[srow][scol] = ra0; *(s16x8*)&As[srow][scol + 8] = ra1;
    *(s16x8*)&Ws[srow][scol] = rw0; *(s16x8*)&Ws[srow][scol + 8] = rw1;
    __syncthreads();

    for (int k0 = 0; k0 < K; k0 += 64) {
        bool hasNext = (k0 + 64) < K;
        if (hasNext) {
            ra0 = *(const s16x8*)(Arow + k0 + 64);
            ra1 = *(const s16x8*)(Arow + k0 + 72);
            rw0 = *(const s16x8*)(Wrow + k0 + 64);
            rw1 = *(const s16x8*)(Wrow + k0 + 72);
        }
#pragma unroll
        for (int kk = 0; kk < 64; kk += 32) {
            s16x8 a0 = *(const s16x8*)&As[wr * 32 + fr][kk + kq];
            s16x8 a1 = *(const s16x8*)&As[wr * 32 + 16 + fr][kk + kq];
            s16x8 b0 = *(const s16x8*)&Ws[wc * 32 + fr][kk + kq];
            s16x8 b1 = *(const s16x8*)&Ws[wc * 32 + 16 + fr][kk + kq];
            acc00 = __builtin_amdgcn_mfma_f32_16x16x32_bf16(a0, b0, acc00, 0, 0, 0);
            acc01 = __builtin_amdgcn_mfma_f32_16x16x32_bf16(a0, b1, acc01, 0, 0, 0);
            acc10 = __builtin_amdgcn_mfma_f32_16x16x32_bf16(a1, b0, acc10, 0, 0, 0);
            acc11 = __builtin_amdgcn_mfma_f32_16x16x32_bf16(a1, b1, acc11, 0, 0, 0);
        }
        __syncthreads();
        if (hasNext) {
            *(s16x8*)&As[srow][scol] = ra0; *(s16x8*)&As[srow][scol + 8] = ra1;
            *(s16x8*)&Ws[srow][scol] = rw0; *(s16x8*)&Ws[srow][scol + 8] = rw1;
            __syncthreads();
        }
    }

    int rbase = (lane >> 4) * 4;
#pragma unroll
    for (int p = 0; p < 4; ++p) {
        int mrow0 = wr * 32 + rbase + p;
        int mrow1 = mrow0 + 16;
        int ncol0 = wc * 32 + fr;
        int ncol1 = ncol0 + 16;
        float v00 = acc00[p], v01 = acc01[p], v10 = acc10[p], v11 = acc11[p];
        long long r0 = m0 + mrow0, r1 = m0 + mrow1;
        int c0 = n0 + ncol0, c1 = n0 + ncol1;
        if (add1) {
            v00 += add1[r0 * lda1 + c0]; v01 += add1[r0 * lda1 + c1];
            v10 += add1[r1 * lda1 + c0]; v11 += add1[r1 * lda1 + c1];
        }
        if (add2) {
            v00 += add2[r0 * lda2 + c0]; v01 += add2[r0 * lda2 + c1];
            v10 += add2[r1 * lda2 + c0]; v11 += add2[r1 * lda2 + c1];
        }
        if (Cb) {
            Cb[r0 * ldc + c0] = f2bf(v00); Cb[r0 * ldc + c1] = f2bf(v01);
            Cb[r1 * ldc + c0] = f2bf(v10); Cb[r1 * ldc + c1] = f2bf(v11);
        } else {
            C[r0 * ldc + c0] = v00; C[r0 * ldc + c1] = v01;
            C[r1 * ldc + c0] = v10; C[r1 * ldc + c1] = v11;
        }
    }
}

// --------- transpose head_v: [k*4+b][n*64+d] -> [(b*16+n)*64+d][k] ---------
__global__ __launch_bounds__(256) void transpose_v_kernel(
    const ushort* __restrict__ vin, ushort* __restrict__ vout)
{
    __shared__ __align__(16) ushort T[64][72];
    int bn = blockIdx.y;
    int b = bn >> 4, n = bn & 15;
    int k0 = blockIdx.x * 64;
    int t = threadIdx.x;
    {
        int kr = t >> 2, dp = (t & 3) * 16;
        const ushort* sp = vin + (((long long)(k0 + kr)) * 4 + b) * DM + n * DHD + dp;
        *(s16x8*)&T[kr][dp] = *(const s16x8*)sp;
        *(s16x8*)&T[kr][dp + 8] = *(const s16x8*)(sp + 8);
    }
    __syncthreads();
    {
        int d = t >> 2, kp = (t & 3) * 16;
        ushort vals[16];
#pragma unroll
        for (int q = 0; q < 16; ++q) vals[q] = T[kp + q][d];
        ushort* dp = vout + ((long long)bn * DHD + d) * KL + k0 + kp;
        *(s16x8*)dp = *(const s16x8*)&vals[0];
        *(s16x8*)(dp + 8) = *(const s16x8*)&vals[8];
    }
}

// --------- corr[n,k] = sum_d (rrb[n,d]-rwb[n,d]) * r_head_k[k,n,d] ---------
__global__ __launch_bounds__(256) void corr_kernel(
    const ushort* __restrict__ r_hk, const float* __restrict__ rwb,
    const float* __restrict__ rrb, float* __restrict__ corr)
{
    int n = blockIdx.y;
    int k = blockIdx.x * 4 + (threadIdx.x >> 6);
    int d = threadIdx.x & 63;
    float diff = rrb[n * DHD + d] - rwb[n * DHD + d];
    float v = diff * bf2f(r_hk[(long long)k * DM + n * DHD + d]);
    v = wave_sum64(v);
    if (d == 0) corr[n * RL + k] = v;
}

// ---------------- MFMA flash rel-shift attention ----------------
// grid (8, 64); 4 waves; wave w owns q-rows [w*16, w*16+16).
// K/V double-buffered; RKs 128-row ring; BDs/Ps wave-private (no barrier);
// ONE __syncthreads() per tile (tile 0: two). Softmax butterflies batched
// across the 4 regs for 4x ILP on the ds_bpermute latency chains.
__global__ __launch_bounds__(256) void attn_mfma_kernel(
    const ushort* __restrict__ hq, const ushort* __restrict__ hk,
    const ushort* __restrict__ hvT, const ushort* __restrict__ rhk,
    const float* __restrict__ corr, ushort* __restrict__ attn_out)
{
    __shared__ __align__(16) ushort Ks[2][64][72];   // [buf][j][d]
    __shared__ __align__(16) ushort VsT[2][64][72];  // [buf][d][j]
    __shared__ __align__(16) ushort RKs[128][72];    // ring [r&127][d]
    __shared__ __align__(16) ushort BDs[64][128];    // wave-private rows; XOR-swz
    __shared__ __align__(16) ushort Ps[64][64];      // wave-private rows; XOR-swz

    int bh = blockIdx.y;
    int b = bh >> 4, n = bh & 15;
    int i0 = blockIdx.x * 64;
    int t = threadIdx.x;
    int lane = t & 63, w = t >> 6;
    int lr16 = lane & 15;
    int lk8 = (lane >> 4) * 8;
    int orow = (lane >> 4) * 4;
    int swzBD = ((lane >> 4) & 3) << 4;

    s16x8 qf0, qf1;
    {
        const ushort* qp = hq + (((long long)(i0 + w * 16 + lr16)) * 4 + b) * DM
                              + n * DHD + lk8;
        qf0 = *(const s16x8*)qp;
        qf1 = *(const s16x8*)(qp + 32);
    }

    f32x4 O[4] = {};
    float m_[4], l_[4];
#pragma unroll
    for (int r = 0; r < 4; ++r) { m_[r] = -INFINITY; l_[r] = 0.0f; }

    int nJ = ((i0 + 575) >> 6) + 1;
    if (nJ > 16) nJ = 16;
    int ka0 = 448 - i0;

    int srow = t >> 2, sdp = (t & 3) * 16;

    {   // prologue: K0,V0 -> buf0; RK rows [ka0, ka0+128) -> ring
        const ushort* kp = hk + (((long long)srow) * 4 + b) * DM + n * DHD + sdp;
        *(s16x8*)&Ks[0][srow][sdp] = *(const s16x8*)kp;
        *(s16x8*)&Ks[0][srow][sdp + 8] = *(const s16x8*)(kp + 8);
        const ushort* vp = hvT + ((long long)bh * DHD + srow) * KL + sdp;
        *(s16x8*)&VsT[0][srow][sdp] = *(const s16x8*)vp;
        *(s16x8*)&VsT[0][srow][sdp + 8] = *(const s16x8*)(vp + 8);
        int rr = t >> 1, dp2 = (t & 1) * 32;
        int rabs = ka0 + rr;
        const ushort* rp = rhk + (long long)rabs * DM + n * DHD + dp2;
        int phys = rabs & 127;
#pragma unroll
        for (int q = 0; q < 4; ++q)
            *(s16x8*)&RKs[phys][dp2 + q * 8] = *(const s16x8*)(rp + q * 8);
    }
    __syncthreads();

    int cur = 0;
    for (int jt = 0; jt < nJ; ++jt) {
        int j0 = jt * 64;
        int ka = ka0 + j0;
        bool hasNext = (jt + 1) < nJ;

        // ---- issue next-tile global loads into registers ----
        s16x8 pk0 = {}, pk1 = {}, pv0 = {}, pv1 = {}, pr0 = {}, pr1 = {};
        if (hasNext) {
            int j0n = j0 + 64;
            const ushort* kp = hk + (((long long)(j0n + srow)) * 4 + b) * DM + n * DHD + sdp;
            pk0 = *(const s16x8*)kp;
            pk1 = *(const s16x8*)(kp + 8);
            const ushort* vp = hvT + ((long long)bh * DHD + srow) * KL + j0n + sdp;
            pv0 = *(const s16x8*)vp;
            pv1 = *(const s16x8*)(vp + 8);
            int rnew = ka + 128 + srow;
            if (rnew < RL) {
                const ushort* rp = rhk + (long long)rnew * DM + n * DHD + sdp;
                pr0 = *(const s16x8*)rp;
                pr1 = *(const s16x8*)(rp + 8);
            }
        }

        // ---- AC (8 MFMA) on Ks[cur] ----
        f32x4 ac[4] = {};
#pragma unroll
        for (int nb = 0; nb < 4; ++nb) {
            s16x8 kb0 = *(const s16x8*)&Ks[cur][nb * 16 + lr16][lk8];
            s16x8 kb1 = *(const s16x8*)&Ks[cur][nb * 16 + lr16][32 + lk8];
            ac[nb] = __builtin_amdgcn_mfma_f32_16x16x32_bf16(qf0, kb0, ac[nb], 0, 0, 0);
            ac[nb] = __builtin_amdgcn_mfma_f32_16x16x32_bf16(qf1, kb1, ac[nb], 0, 0, 0);
        }
        // ---- BD: tile0 all 128 cols, later tiles only new 64 ----
        int nb0 = (jt == 0) ? 0 : 4;
        for (int nb = nb0; nb < 8; ++nb) {
            int kk = nb * 16 + lr16;
            int rabs = ka + kk;
            int phys = rabs & 127;
            f32x4 bd = {};
            s16x8 rb0 = *(const s16x8*)&RKs[phys][lk8];
            s16x8 rb1 = *(const s16x8*)&RKs[phys][32 + lk8];
            bd = __builtin_amdgcn_mfma_f32_16x16x32_bf16(qf0, rb0, bd, 0, 0, 0);
            bd = __builtin_amdgcn_mfma_f32_16x16x32_bf16(qf1, rb1, bd, 0, 0, 0);
            float cadd = (rabs < RL) ? corr[n * RL + rabs] : 0.0f;
            int colw = phys ^ swzBD;
#pragma unroll
            for (int reg = 0; reg < 4; ++reg)
                BDs[w * 16 + orow + reg][colw] = f2bf(bd[reg] + cadd);
        }
        if (jt == 0) __syncthreads();   // cross-wave WAR on ring (tile0 only)

        // ---- rel-shift assembly + batched online softmax ----
        float pvv[4][4], rowm[4];
#pragma unroll
        for (int reg = 0; reg < 4; ++reg) {
            int il = w * 16 + orow + reg;
            int i = i0 + il;
            rowm[reg] = -INFINITY;
#pragma unroll
            for (int nb = 0; nb < 4; ++nb) {
                int jc = nb * 16 + lr16;
                int j = j0 + jc;
                float s = -INFINITY;
                if (j <= i + M_LEN) {
                    int phys = (j + 511 - i) & 127;
                    s = (ac[nb][reg] + bf2f(BDs[il][phys ^ swzBD])) * ATT_SCALE;
                }
                pvv[reg][nb] = s;
                rowm[reg] = fmaxf(rowm[reg], s);
            }
        }
#pragma unroll
        for (int st = 1; st <= 8; st <<= 1)
#pragma unroll
            for (int reg = 0; reg < 4; ++reg)
                rowm[reg] = fmaxf(rowm[reg], __shfl_xor(rowm[reg], st));
        float rs[4], alpha[4];
#pragma unroll
        for (int reg = 0; reg < 4; ++reg) {
            int il = w * 16 + orow + reg;
            float newm = fmaxf(m_[reg], rowm[reg]);
            alpha[reg] = __expf(m_[reg] - newm);
            m_[reg] = newm;
            rs[reg] = 0.0f;
#pragma unroll
            for (int nb = 0; nb < 4; ++nb) {
                float p = __expf(pvv[reg][nb] - newm);
                rs[reg] += p;
                int jc = nb * 16 + lr16;
                int colp = (((jc >> 3) ^ (il & 7)) << 3) | (jc & 7);
                Ps[il][colp] = f2bf(p);
            }
        }
#pragma unroll
        for (int st = 1; st <= 8; st <<= 1)
#pragma unroll
            for (int reg = 0; reg < 4; ++reg)
                rs[reg] += __shfl_xor(rs[reg], st);
#pragma unroll
        for (int reg = 0; reg < 4; ++reg) {
            l_[reg] = l_[reg] * alpha[reg] + rs[reg];
#pragma unroll
            for (int nb = 0; nb < 4; ++nb) O[nb][reg] *= alpha[reg];
        }

        // ---- PV (8 MFMA) on VsT[cur]; Ps rows wave-private ----
        {
            int prow = w * 16 + lr16;
            int rh = prow & 7;
#pragma unroll
            for (int kc = 0; kc < 2; ++kc) {
                int blk = kc * 4 + (lane >> 4);
                s16x8 pa = *(const s16x8*)&Ps[prow][(blk ^ rh) << 3];
#pragma unroll
                for (int nb = 0; nb < 4; ++nb) {
                    s16x8 vb = *(const s16x8*)&VsT[cur][nb * 16 + lr16][kc * 32 + lk8];
                    O[nb] = __builtin_amdgcn_mfma_f32_16x16x32_bf16(pa, vb, O[nb], 0, 0, 0);
                }
            }
        }

        // ---- stage prefetched regs ----
        if (hasNext) {
            *(s16x8*)&Ks[cur ^ 1][srow][sdp] = pk0;
            *(s16x8*)&Ks[cur ^ 1][srow][sdp + 8] = pk1;
            *(s16x8*)&VsT[cur ^ 1][srow][sdp] = pv0;
            *(s16x8*)&VsT[cur ^ 1][srow][sdp + 8] = pv1;
            int phys = (ka + 128 + srow) & 127;
            *(s16x8*)&RKs[phys][sdp] = pr0;
            *(s16x8*)&RKs[phys][sdp + 8] = pr1;
        }
        __syncthreads();
        cur ^= 1;
    }

    // ---- epilogue ----
#pragma unroll
    for (int reg = 0; reg < 4; ++reg) {
        int il = w * 16 + orow + reg;
        long long i = i0 + il;
        float inv = 1.0f / l_[reg];
#pragma unroll
        for (int nb = 0; nb < 4; ++nb)
            attn_out[(i * 4 + b) * DM + n * DHD + nb * 16 + lr16] = f2bf(O[nb][reg] * inv);
    }
}

extern "C" void kernel_launch(void* const* d_in, const int* in_sizes, int n_in,
                              void* d_out, int out_size, void* d_ws, size_t ws_size,
                              hipStream_t stream) {
    const float* w       = (const float*)d_in[0];
    const float* r       = (const float*)d_in[1];
    const float* rwb     = (const float*)d_in[2];
    const float* rrb     = (const float*)d_in[3];
    const float* mems    = (const float*)d_in[4];
    const float* gamma_q = (const float*)d_in[5];
    const float* beta_q  = (const float*)d_in[6];
    const float* gamma_kv= (const float*)d_in[7];
    const float* beta_kv = (const float*)d_in[8];
    const float* Wq      = (const float*)d_in[9];
    const float* Wiq     = (const float*)d_in[10];
    const float* Wk      = (const float*)d_in[11];
    const float* Wv      = (const float*)d_in[12];
    const float* Wr      = (const float*)d_in[13];
    const float* Wintra  = (const float*)d_in[14];
    const float* Winter  = (const float*)d_in[15];
    float* out = (float*)d_out;
    float* ws = (float*)d_ws;

    float* tmp  = ws;                         // 524,288 f32
    float* corr = tmp + 524288;               // 16,384 f32

    ushort* w_norm_bf  = (ushort*)(corr + 16384);
    ushort* kv_norm_bf = w_norm_bf + 2097152;
    ushort* head_q_bf  = kv_norm_bf + 4194304;   // includes r_w_bias
    ushort* head_k_bf  = head_q_bf + 2097152;
    ushort* head_v_bf  = head_k_bf + 4194304;    // contiguous after head_k
    ushort* head_vT_bf = head_v_bf + 4194304;
    ushort* r_hk_bf    = head_vT_bf + 4194304;
    ushort* attn_o_bf  = r_hk_bf + 1048576;
    ushort* r_bf       = attn_o_bf + 2097152;
    ushort* Wk_bf      = r_bf + 1048576;
    ushort* Wv_bf      = Wk_bf + 1048576;        // contiguous after Wk
    ushort* Wq_bf      = Wv_bf + 1048576;
    ushort* Wiq_bf     = Wq_bf + 262144;
    ushort* Wr_bf      = Wiq_bf + 262144;
    ushort* Wintra_bf  = Wr_bf + 262144;
    ushort* Winter_bf  = Wintra_bf + 262144;

    group_ln_kernel<<<dim3(Q_LEN * BSZ * NG), 64, 0, stream>>>(w, gamma_q, beta_q, w_norm_bf);
    kv_ln_kernel<<<dim3(KL * BSZ), 256, 0, stream>>>(mems, w, gamma_kv, beta_kv, kv_norm_bf);

    cast8_kernel<<<dim3(4352), 256, 0, stream>>>(
        r, Wk, Wv, Wq, Wiq, Wr, Wintra, Winter,
        r_bf, Wk_bf, Wv_bf, Wq_bf, Wiq_bf, Wr_bf, Wintra_bf, Winter_bf);

    // head_k & head_v in ONE dispatch
    gemm_bf16_nt<<<dim3(16, 64, 2), 256, 0, stream>>>(
        kv_norm_bf, 0, DM, Wk_bf, 1048576, DM, nullptr, head_k_bf, 4194304, DM,
        KL * BSZ, DM, DM, nullptr, 0, 0, nullptr, 0, 0);
    transpose_v_kernel<<<dim3(16, 64), 256, 0, stream>>>(head_v_bf, head_vT_bf);

    // q_global -> tmp (f32)
    gemm_bf16_nt<<<dim3(4, 32, 1), 256, 0, stream>>>(
        w_norm_bf, 0, DM, Wiq_bf, 0, DM, tmp, nullptr, 0, DGRP, Q_LEN * BSZ, DGRP, DM,
        nullptr, 0, 0, nullptr, 0, 0);
    // head_q = grouped(w_norm*Wq^T) + q_global + rwb  -> bf16
    gemm_bf16_nt<<<dim3(4, 32, 4), 256, 0, stream>>>(
        w_norm_bf, DGRP, DM, Wq_bf, DGRP * DGRP, DGRP, nullptr, head_q_bf, DGRP, DM,
        Q_LEN * BSZ, DGRP, DGRP, tmp, 0, DGRP, rwb, DGRP, 0);
    // r_head_k -> bf16
    gemm_bf16_nt<<<dim3(4, 16, 4), 256, 0, stream>>>(
        r_bf, DGRP, DM, Wr_bf, DGRP * DGRP, DGRP, nullptr, r_hk_bf, DGRP, DM,
        RL, DGRP, DGRP, nullptr, 0, 0, nullptr, 0, 0);

    corr_kernel<<<dim3(RL / 4, NH), 256, 0, stream>>>(r_hk_bf, rwb, rrb, corr);

    attn_mfma_kernel<<<dim3(Q_LEN / 64, BSZ * NH), 256, 0, stream>>>(
        head_q_bf, head_k_bf, head_vT_bf, r_hk_bf, corr, attn_o_bf);

    // inter -> tmp (f32)
    gemm_bf16_nt<<<dim3(4, 32, 1), 256, 0, stream>>>(
        attn_o_bf, 0, DM, Winter_bf, 0, DM, tmp, nullptr, 0, DGRP, Q_LEN * BSZ, DGRP, DM,
        nullptr, 0, 0, nullptr, 0, 0);
    // out = grouped(attn_o*Wintra^T) + inter + w
    gemm_bf16_nt<<<dim3(4, 32, 4), 256, 0, stream>>>(
        attn_o_bf, DGRP, DM, Wintra_bf, DGRP * DGRP, DGRP, out, nullptr, DGRP, DM,
        Q_LEN * BSZ, DGRP, DGRP, tmp, 0, DGRP, w, DGRP, DM);
}

// Round 11
// 163.577 us; speedup vs baseline: 5.1153x; 1.0684x over previous
//
#include <hip/hip_runtime.h>
#include <math.h>

#define Q_LEN 512
#define M_LEN 512
#define KL    1024
#define BSZ   4
#define DM    1024
#define NH    16
#define DHD   64
#define NG    4
#define DGRP  256
#define RL    1024
#define LN_EPS 1e-6f
#define ATT_SCALE 0.125f

typedef short s16x8 __attribute__((ext_vector_type(8)));
typedef float f32x4 __attribute__((ext_vector_type(4)));

__device__ __forceinline__ float wave_sum64(float v) {
#pragma unroll
    for (int off = 32; off > 0; off >>= 1) v += __shfl_xor(v, off);
    return v;
}

__device__ __forceinline__ ushort f2bf(float f) {
    unsigned u = __float_as_uint(f);
    unsigned r = (u + 0x7fffu + ((u >> 16) & 1u)) >> 16;   // RNE
    return (ushort)r;
}
__device__ __forceinline__ float bf2f(ushort u) {
    return __uint_as_float(((unsigned)u) << 16);
}

// ---------------- f32 -> bf16 cast of r, Wk, Wv, Wr ----------------
__global__ __launch_bounds__(256) void cast4_kernel(
    const float* p0, const float* p1, const float* p2, const float* p3,
    ushort* d0, ushort* d1, ushort* d2, ushort* d3)
{
    int bid = blockIdx.x;
    const float* s; ushort* d; int off;
    if      (bid < 1024) { s = p0; d = d0; off = bid; }
    else if (bid < 2048) { s = p1; d = d1; off = bid - 1024; }
    else if (bid < 3072) { s = p2; d = d2; off = bid - 2048; }
    else                 { s = p3; d = d3; off = bid - 3072; }
    int i = off * 1024 + threadIdx.x * 4;
    float4 v = *(const float4*)(s + i);
    ushort4 o;
    o.x = f2bf(v.x); o.y = f2bf(v.y); o.z = f2bf(v.z); o.w = f2bf(v.w);
    *(ushort4*)(d + i) = o;
}

// ---- augmented weights: W'[g][o][k] = Wfull[o][k] + (k>>8==g ? Wg[g][o][k&255] : 0)
// bid<1024: (Wq,Wiq)->Wq_aug ; else: (Wintra,Winter)->Wo_aug
__global__ __launch_bounds__(256) void augment_kernel(
    const float* __restrict__ Wg0, const float* __restrict__ Wf0, ushort* __restrict__ Wo0,
    const float* __restrict__ Wg1, const float* __restrict__ Wf1, ushort* __restrict__ Wo1)
{
    int bid = blockIdx.x;
    const float* Wg; const float* Wf; ushort* Wo; int off;
    if (bid < 1024) { Wg = Wg0; Wf = Wf0; Wo = Wo0; off = bid; }
    else            { Wg = Wg1; Wf = Wf1; Wo = Wo1; off = bid - 1024; }
    int idx = off * 1024 + threadIdx.x * 4;      // over 4*256*1024
    int g = idx >> 18;
    int o = (idx >> 10) & 255;
    int k = idx & 1023;
    float4 v = *(const float4*)(Wf + o * 1024 + k);
    if ((k >> 8) == g) {
        float4 vg = *(const float4*)(Wg + ((g * 256 + o) << 8) + (k & 255));
        v.x += vg.x; v.y += vg.y; v.z += vg.z; v.w += vg.w;
    }
    ushort4 u;
    u.x = f2bf(v.x); u.y = f2bf(v.y); u.z = f2bf(v.z); u.w = f2bf(v.w);
    *(ushort4*)(Wo + idx) = u;
}

// ---------------- group LayerNorm for w (G=4 groups of 256) -> bf16 --------
__global__ __launch_bounds__(64) void group_ln_kernel(
    const float* __restrict__ w, const float* __restrict__ gamma,
    const float* __restrict__ beta, ushort* __restrict__ out)
{
    int bid = blockIdx.x;              // (q*BSZ + b)*NG + g
    int g = bid & (NG - 1);
    long long row = bid >> 2;
    int t = threadIdx.x;
    long long base = row * DM + g * DGRP + t * 4;
    float4 x = *(const float4*)(w + base);
    float mean = wave_sum64(x.x + x.y + x.z + x.w) * (1.0f / 256.0f);
    float dx = x.x - mean, dy = x.y - mean, dz = x.z - mean, dw = x.w - mean;
    float ss = wave_sum64(dx * dx + dy * dy + dz * dz + dw * dw);
    float inv = 1.0f / (sqrtf(ss * (1.0f / 255.0f)) + LN_EPS);   // ddof=1
    int db = g * DGRP + t * 4;
    float4 ga = *(const float4*)(gamma + db);
    float4 be = *(const float4*)(beta + db);
    ushort4 o;
    o.x = f2bf(ga.x * (dx * inv) + be.x);
    o.y = f2bf(ga.y * (dy * inv) + be.y);
    o.z = f2bf(ga.z * (dz * inv) + be.z);
    o.w = f2bf(ga.w * (dw * inv) + be.w);
    *(ushort4*)(out + base) = o;
}

// ---------------- full LayerNorm for kv = concat(mems, w) -> bf16 ----------
__global__ __launch_bounds__(256) void kv_ln_kernel(
    const float* __restrict__ mems, const float* __restrict__ w,
    const float* __restrict__ gamma, const float* __restrict__ beta,
    ushort* __restrict__ out)
{
    int row = blockIdx.x;              // k*BSZ + b
    int k = row >> 2, b = row & 3;
    const float* src = (k < M_LEN) ? (mems + ((long long)k * BSZ + b) * DM)
                                   : (w + ((long long)(k - M_LEN) * BSZ + b) * DM);
    int t = threadIdx.x;
    float4 x = *(const float4*)(src + t * 4);
    __shared__ float red[4];
    float s = wave_sum64(x.x + x.y + x.z + x.w);
    int wv = t >> 6, ln = t & 63;
    if (ln == 0) red[wv] = s;
    __syncthreads();
    float mean = (red[0] + red[1] + red[2] + red[3]) * (1.0f / 1024.0f);
    float dx = x.x - mean, dy = x.y - mean, dz = x.z - mean, dw = x.w - mean;
    float ss = wave_sum64(dx * dx + dy * dy + dz * dz + dw * dw);
    __syncthreads();
    if (ln == 0) red[wv] = ss;
    __syncthreads();
    float var = (red[0] + red[1] + red[2] + red[3]) * (1.0f / 1023.0f);
    float inv = 1.0f / (sqrtf(var) + LN_EPS);
    int db = t * 4;
    float4 ga = *(const float4*)(gamma + db);
    float4 be = *(const float4*)(beta + db);
    ushort4 o;
    o.x = f2bf(ga.x * (dx * inv) + be.x);
    o.y = f2bf(ga.y * (dy * inv) + be.y);
    o.z = f2bf(ga.z * (dz * inv) + be.z);
    o.w = f2bf(ga.w * (dw * inv) + be.w);
    *(ushort4*)(out + (long long)row * DM + db) = o;
}

// ------ 128x128-tile bf16 MFMA GEMM  Cb = A[M,K] * W[N,K]^T (bf16 out) -----
// 4 waves, each owns a 64x64 quadrant (4x4 of 16x16). K-step 32, reg prefetch.
__global__ __launch_bounds__(256) void gemm128_bf16_nt(
    const ushort* __restrict__ A, int lda,
    const ushort* __restrict__ W, long long wZ, int ldw,
    ushort* __restrict__ Cb, long long cZ, int ldc, int K)
{
    int z = blockIdx.z;
    W += (long long)z * wZ;
    Cb += (long long)z * cZ;
    int m0 = blockIdx.y * 128, n0 = blockIdx.x * 128;
    int t = threadIdx.x, lane = t & 63, w = t >> 6;
    int wr = w >> 1, wc = w & 1;
    int fr = lane & 15, kq = (lane >> 4) * 8;
    int srow = t >> 1, scol = (t & 1) * 16;

    __shared__ __align__(16) ushort As[128][40];   // 2-way banks (free)
    __shared__ __align__(16) ushort Ws[128][40];

    const ushort* Ar = A + (long long)(m0 + srow) * lda + scol;
    const ushort* Wr = W + (long long)(n0 + srow) * ldw + scol;

    f32x4 acc[16] = {};

    s16x8 a0 = *(const s16x8*)Ar, a1 = *(const s16x8*)(Ar + 8);
    s16x8 b0 = *(const s16x8*)Wr, b1 = *(const s16x8*)(Wr + 8);
    *(s16x8*)&As[srow][scol] = a0; *(s16x8*)&As[srow][scol + 8] = a1;
    *(s16x8*)&Ws[srow][scol] = b0; *(s16x8*)&Ws[srow][scol + 8] = b1;
    __syncthreads();

    for (int k0 = 0; k0 < K; k0 += 32) {
        bool more = (k0 + 32) < K;
        if (more) {
            a0 = *(const s16x8*)(Ar + k0 + 32); a1 = *(const s16x8*)(Ar + k0 + 40);
            b0 = *(const s16x8*)(Wr + k0 + 32); b1 = *(const s16x8*)(Wr + k0 + 40);
        }
        s16x8 af[4], bf_[4];
#pragma unroll
        for (int rb = 0; rb < 4; ++rb)
            af[rb] = *(const s16x8*)&As[wr * 64 + rb * 16 + fr][kq];
#pragma unroll
        for (int cb = 0; cb < 4; ++cb)
            bf_[cb] = *(const s16x8*)&Ws[wc * 64 + cb * 16 + fr][kq];
#pragma unroll
        for (int rb = 0; rb < 4; ++rb)
#pragma unroll
            for (int cb = 0; cb < 4; ++cb)
                acc[rb * 4 + cb] = __builtin_amdgcn_mfma_f32_16x16x32_bf16(
                    af[rb], bf_[cb], acc[rb * 4 + cb], 0, 0, 0);
        __syncthreads();
        if (more) {
            *(s16x8*)&As[srow][scol] = a0; *(s16x8*)&As[srow][scol + 8] = a1;
            *(s16x8*)&Ws[srow][scol] = b0; *(s16x8*)&Ws[srow][scol + 8] = b1;
            __syncthreads();
        }
    }

    int rbase = (lane >> 4) * 4;
#pragma unroll
    for (int rb = 0; rb < 4; ++rb)
#pragma unroll
        for (int p = 0; p < 4; ++p) {
            long long row = m0 + wr * 64 + rb * 16 + rbase + p;
            ushort* crow = Cb + row * ldc + n0 + wc * 64 + fr;
#pragma unroll
            for (int cb = 0; cb < 4; ++cb)
                crow[cb * 16] = f2bf(acc[rb * 4 + cb][p]);
        }
}

// ------ 64x64-tile bf16 MFMA GEMM (BK=64 + reg prefetch), f32/bf16 out -----
__global__ __launch_bounds__(256) void gemm_bf16_nt(
    const ushort* __restrict__ A, long long aZ, int lda,
    const ushort* __restrict__ W, long long wZ, int ldw,
    float* __restrict__ C, ushort* __restrict__ Cb, long long cZ, int ldc,
    int M, int N, int K,
    const float* __restrict__ add1, long long a1Z, int lda1,
    const float* __restrict__ add2, long long a2Z, int lda2)
{
    int z = blockIdx.z;
    A += (long long)z * aZ;
    W += (long long)z * wZ;
    if (C)  C += (long long)z * cZ;
    if (Cb) Cb += (long long)z * cZ;
    if (add1) add1 += (long long)z * a1Z;
    if (add2) add2 += (long long)z * a2Z;
    int m0 = blockIdx.y * 64, n0 = blockIdx.x * 64;
    int t = threadIdx.x;
    int lane = t & 63, wid = t >> 6;
    int wr = wid >> 1, wc = wid & 1;
    int srow = t >> 2, scol = (t & 3) * 16;
    int fr = lane & 15, kq = (lane >> 4) * 8;

    __shared__ __align__(16) ushort As[64][72];
    __shared__ __align__(16) ushort Ws[64][72];

    f32x4 acc00 = {}, acc01 = {}, acc10 = {}, acc11 = {};

    const ushort* Arow = A + (long long)(m0 + srow) * lda + scol;
    const ushort* Wrow = W + (long long)(n0 + srow) * ldw + scol;

    s16x8 ra0 = *(const s16x8*)Arow;
    s16x8 ra1 = *(const s16x8*)(Arow + 8);
    s16x8 rw0 = *(const s16x8*)Wrow;
    s16x8 rw1 = *(const s16x8*)(Wrow + 8);
    *(s16x8*)&As[srow][scol] = ra0; *(s16x8*)&As[srow][scol + 8] = ra1;
    *(s16x8*)&Ws[srow][scol] = rw0; *(s16x8*)&Ws[srow][scol + 8] = rw1;
    __syncthreads();

    for (int k0 = 0; k0 < K; k0 += 64) {
        bool hasNext = (k0 + 64) < K;
        if (hasNext) {
            ra0 = *(const s16x8*)(Arow + k0 + 64);
            ra1 = *(const s16x8*)(Arow + k0 + 72);
            rw0 = *(const s16x8*)(Wrow + k0 + 64);
            rw1 = *(const s16x8*)(Wrow + k0 + 72);
        }
#pragma unroll
        for (int kk = 0; kk < 64; kk += 32) {
            s16x8 a0 = *(const s16x8*)&As[wr * 32 + fr][kk + kq];
            s16x8 a1 = *(const s16x8*)&As[wr * 32 + 16 + fr][kk + kq];
            s16x8 b0 = *(const s16x8*)&Ws[wc * 32 + fr][kk + kq];
            s16x8 b1 = *(const s16x8*)&Ws[wc * 32 + 16 + fr][kk + kq];
            acc00 = __builtin_amdgcn_mfma_f32_16x16x32_bf16(a0, b0, acc00, 0, 0, 0);
            acc01 = __builtin_amdgcn_mfma_f32_16x16x32_bf16(a0, b1, acc01, 0, 0, 0);
            acc10 = __builtin_amdgcn_mfma_f32_16x16x32_bf16(a1, b0, acc10, 0, 0, 0);
            acc11 = __builtin_amdgcn_mfma_f32_16x16x32_bf16(a1, b1, acc11, 0, 0, 0);
        }
        __syncthreads();
        if (hasNext) {
            *(s16x8*)&As[srow][scol] = ra0; *(s16x8*)&As[srow][scol + 8] = ra1;
            *(s16x8*)&Ws[srow][scol] = rw0; *(s16x8*)&Ws[srow][scol + 8] = rw1;
            __syncthreads();
        }
    }

    int rbase = (lane >> 4) * 4;
#pragma unroll
    for (int p = 0; p < 4; ++p) {
        int mrow0 = wr * 32 + rbase + p;
        int mrow1 = mrow0 + 16;
        int ncol0 = wc * 32 + fr;
        int ncol1 = ncol0 + 16;
        float v00 = acc00[p], v01 = acc01[p], v10 = acc10[p], v11 = acc11[p];
        long long r0 = m0 + mrow0, r1 = m0 + mrow1;
        int c0 = n0 + ncol0, c1 = n0 + ncol1;
        if (add1) {
            v00 += add1[r0 * lda1 + c0]; v01 += add1[r0 * lda1 + c1];
            v10 += add1[r1 * lda1 + c0]; v11 += add1[r1 * lda1 + c1];
        }
        if (add2) {
            v00 += add2[r0 * lda2 + c0]; v01 += add2[r0 * lda2 + c1];
            v10 += add2[r1 * lda2 + c0]; v11 += add2[r1 * lda2 + c1];
        }
        if (Cb) {
            Cb[r0 * ldc + c0] = f2bf(v00); Cb[r0 * ldc + c1] = f2bf(v01);
            Cb[r1 * ldc + c0] = f2bf(v10); Cb[r1 * ldc + c1] = f2bf(v11);
        } else {
            C[r0 * ldc + c0] = v00; C[r0 * ldc + c1] = v01;
            C[r1 * ldc + c0] = v10; C[r1 * ldc + c1] = v11;
        }
    }
}

// --------- transpose head_v: [k*4+b][n*64+d] -> [(b*16+n)*64+d][k] ---------
__global__ __launch_bounds__(256) void transpose_v_kernel(
    const ushort* __restrict__ vin, ushort* __restrict__ vout)
{
    __shared__ __align__(16) ushort T[64][72];
    int bn = blockIdx.y;
    int b = bn >> 4, n = bn & 15;
    int k0 = blockIdx.x * 64;
    int t = threadIdx.x;
    {
        int kr = t >> 2, dp = (t & 3) * 16;
        const ushort* sp = vin + (((long long)(k0 + kr)) * 4 + b) * DM + n * DHD + dp;
        *(s16x8*)&T[kr][dp] = *(const s16x8*)sp;
        *(s16x8*)&T[kr][dp + 8] = *(const s16x8*)(sp + 8);
    }
    __syncthreads();
    {
        int d = t >> 2, kp = (t & 3) * 16;
        ushort vals[16];
#pragma unroll
        for (int q = 0; q < 16; ++q) vals[q] = T[kp + q][d];
        ushort* dp = vout + ((long long)bn * DHD + d) * KL + k0 + kp;
        *(s16x8*)dp = *(const s16x8*)&vals[0];
        *(s16x8*)(dp + 8) = *(const s16x8*)&vals[8];
    }
}

// --------- corr[n,k] = sum_d (rrb[n,d]-rwb[n,d]) * r_head_k[k,n,d] ---------
__global__ __launch_bounds__(256) void corr_kernel(
    const ushort* __restrict__ r_hk, const float* __restrict__ rwb,
    const float* __restrict__ rrb, float* __restrict__ corr)
{
    int n = blockIdx.y;
    int k = blockIdx.x * 4 + (threadIdx.x >> 6);
    int d = threadIdx.x & 63;
    float diff = rrb[n * DHD + d] - rwb[n * DHD + d];
    float v = diff * bf2f(r_hk[(long long)k * DM + n * DHD + d]);
    v = wave_sum64(v);
    if (d == 0) corr[n * RL + k] = v;
}

// ---------------- MFMA flash rel-shift attention (unchanged from R10) ------
__global__ __launch_bounds__(256) void attn_mfma_kernel(
    const ushort* __restrict__ hq, const ushort* __restrict__ hk,
    const ushort* __restrict__ hvT, const ushort* __restrict__ rhk,
    const float* __restrict__ corr, ushort* __restrict__ attn_out)
{
    __shared__ __align__(16) ushort Ks[2][64][72];
    __shared__ __align__(16) ushort VsT[2][64][72];
    __shared__ __align__(16) ushort RKs[128][72];
    __shared__ __align__(16) ushort BDs[64][128];
    __shared__ __align__(16) ushort Ps[64][64];

    int bh = blockIdx.y;
    int b = bh >> 4, n = bh & 15;
    int i0 = blockIdx.x * 64;
    int t = threadIdx.x;
    int lane = t & 63, w = t >> 6;
    int lr16 = lane & 15;
    int lk8 = (lane >> 4) * 8;
    int orow = (lane >> 4) * 4;
    int swzBD = ((lane >> 4) & 3) << 4;

    s16x8 qf0, qf1;
    {
        const ushort* qp = hq + (((long long)(i0 + w * 16 + lr16)) * 4 + b) * DM
                              + n * DHD + lk8;
        qf0 = *(const s16x8*)qp;
        qf1 = *(const s16x8*)(qp + 32);
    }

    f32x4 O[4] = {};
    float m_[4], l_[4];
#pragma unroll
    for (int r = 0; r < 4; ++r) { m_[r] = -INFINITY; l_[r] = 0.0f; }

    int nJ = ((i0 + 575) >> 6) + 1;
    if (nJ > 16) nJ = 16;
    int ka0 = 448 - i0;

    int srow = t >> 2, sdp = (t & 3) * 16;

    {
        const ushort* kp = hk + (((long long)srow) * 4 + b) * DM + n * DHD + sdp;
        *(s16x8*)&Ks[0][srow][sdp] = *(const s16x8*)kp;
        *(s16x8*)&Ks[0][srow][sdp + 8] = *(const s16x8*)(kp + 8);
        const ushort* vp = hvT + ((long long)bh * DHD + srow) * KL + sdp;
        *(s16x8*)&VsT[0][srow][sdp] = *(const s16x8*)vp;
        *(s16x8*)&VsT[0][srow][sdp + 8] = *(const s16x8*)(vp + 8);
        int rr = t >> 1, dp2 = (t & 1) * 32;
        int rabs = ka0 + rr;
        const ushort* rp = rhk + (long long)rabs * DM + n * DHD + dp2;
        int phys = rabs & 127;
#pragma unroll
        for (int q = 0; q < 4; ++q)
            *(s16x8*)&RKs[phys][dp2 + q * 8] = *(const s16x8*)(rp + q * 8);
    }
    __syncthreads();

    int cur = 0;
    for (int jt = 0; jt < nJ; ++jt) {
        int j0 = jt * 64;
        int ka = ka0 + j0;
        bool hasNext = (jt + 1) < nJ;

        s16x8 pk0 = {}, pk1 = {}, pv0 = {}, pv1 = {}, pr0 = {}, pr1 = {};
        if (hasNext) {
            int j0n = j0 + 64;
            const ushort* kp = hk + (((long long)(j0n + srow)) * 4 + b) * DM + n * DHD + sdp;
            pk0 = *(const s16x8*)kp;
            pk1 = *(const s16x8*)(kp + 8);
            const ushort* vp = hvT + ((long long)bh * DHD + srow) * KL + j0n + sdp;
            pv0 = *(const s16x8*)vp;
            pv1 = *(const s16x8*)(vp + 8);
            int rnew = ka + 128 + srow;
            if (rnew < RL) {
                const ushort* rp = rhk + (long long)rnew * DM + n * DHD + sdp;
                pr0 = *(const s16x8*)rp;
                pr1 = *(const s16x8*)(rp + 8);
            }
        }

        f32x4 ac[4] = {};
#pragma unroll
        for (int nb = 0; nb < 4; ++nb) {
            s16x8 kb0 = *(const s16x8*)&Ks[cur][nb * 16 + lr16][lk8];
            s16x8 kb1 = *(const s16x8*)&Ks[cur][nb * 16 + lr16][32 + lk8];
            ac[nb] = __builtin_amdgcn_mfma_f32_16x16x32_bf16(qf0, kb0, ac[nb], 0, 0, 0);
            ac[nb] = __builtin_amdgcn_mfma_f32_16x16x32_bf16(qf1, kb1, ac[nb], 0, 0, 0);
        }
        int nb0 = (jt == 0) ? 0 : 4;
        for (int nb = nb0; nb < 8; ++nb) {
            int kk = nb * 16 + lr16;
            int rabs = ka + kk;
            int phys = rabs & 127;
            f32x4 bd = {};
            s16x8 rb0 = *(const s16x8*)&RKs[phys][lk8];
            s16x8 rb1 = *(const s16x8*)&RKs[phys][32 + lk8];
            bd = __builtin_amdgcn_mfma_f32_16x16x32_bf16(qf0, rb0, bd, 0, 0, 0);
            bd = __builtin_amdgcn_mfma_f32_16x16x32_bf16(qf1, rb1, bd, 0, 0, 0);
            float cadd = (rabs < RL) ? corr[n * RL + rabs] : 0.0f;
            int colw = phys ^ swzBD;
#pragma unroll
            for (int reg = 0; reg < 4; ++reg)
                BDs[w * 16 + orow + reg][colw] = f2bf(bd[reg] + cadd);
        }
        if (jt == 0) __syncthreads();

        float pvv[4][4], rowm[4];
#pragma unroll
        for (int reg = 0; reg < 4; ++reg) {
            int il = w * 16 + orow + reg;
            int i = i0 + il;
            rowm[reg] = -INFINITY;
#pragma unroll
            for (int nb = 0; nb < 4; ++nb) {
                int jc = nb * 16 + lr16;
                int j = j0 + jc;
                float s = -INFINITY;
                if (j <= i + M_LEN) {
                    int phys = (j + 511 - i) & 127;
                    s = (ac[nb][reg] + bf2f(BDs[il][phys ^ swzBD])) * ATT_SCALE;
                }
                pvv[reg][nb] = s;
                rowm[reg] = fmaxf(rowm[reg], s);
            }
        }
#pragma unroll
        for (int st = 1; st <= 8; st <<= 1)
#pragma unroll
            for (int reg = 0; reg < 4; ++reg)
                rowm[reg] = fmaxf(rowm[reg], __shfl_xor(rowm[reg], st));
        float rs[4], alpha[4];
#pragma unroll
        for (int reg = 0; reg < 4; ++reg) {
            int il = w * 16 + orow + reg;
            float newm = fmaxf(m_[reg], rowm[reg]);
            alpha[reg] = __expf(m_[reg] - newm);
            m_[reg] = newm;
            rs[reg] = 0.0f;
#pragma unroll
            for (int nb = 0; nb < 4; ++nb) {
                float p = __expf(pvv[reg][nb] - newm);
                rs[reg] += p;
                int jc = nb * 16 + lr16;
                int colp = (((jc >> 3) ^ (il & 7)) << 3) | (jc & 7);
                Ps[il][colp] = f2bf(p);
            }
        }
#pragma unroll
        for (int st = 1; st <= 8; st <<= 1)
#pragma unroll
            for (int reg = 0; reg < 4; ++reg)
                rs[reg] += __shfl_xor(rs[reg], st);
#pragma unroll
        for (int reg = 0; reg < 4; ++reg) {
            l_[reg] = l_[reg] * alpha[reg] + rs[reg];
#pragma unroll
            for (int nb = 0; nb < 4; ++nb) O[nb][reg] *= alpha[reg];
        }

        {
            int prow = w * 16 + lr16;
            int rh = prow & 7;
#pragma unroll
            for (int kc = 0; kc < 2; ++kc) {
                int blk = kc * 4 + (lane >> 4);
                s16x8 pa = *(const s16x8*)&Ps[prow][(blk ^ rh) << 3];
#pragma unroll
                for (int nb = 0; nb < 4; ++nb) {
                    s16x8 vb = *(const s16x8*)&VsT[cur][nb * 16 + lr16][kc * 32 + lk8];
                    O[nb] = __builtin_amdgcn_mfma_f32_16x16x32_bf16(pa, vb, O[nb], 0, 0, 0);
                }
            }
        }

        if (hasNext) {
            *(s16x8*)&Ks[cur ^ 1][srow][sdp] = pk0;
            *(s16x8*)&Ks[cur ^ 1][srow][sdp + 8] = pk1;
            *(s16x8*)&VsT[cur ^ 1][srow][sdp] = pv0;
            *(s16x8*)&VsT[cur ^ 1][srow][sdp + 8] = pv1;
            int phys = (ka + 128 + srow) & 127;
            *(s16x8*)&RKs[phys][sdp] = pr0;
            *(s16x8*)&RKs[phys][sdp + 8] = pr1;
        }
        __syncthreads();
        cur ^= 1;
    }

#pragma unroll
    for (int reg = 0; reg < 4; ++reg) {
        int il = w * 16 + orow + reg;
        long long i = i0 + il;
        float inv = 1.0f / l_[reg];
#pragma unroll
        for (int nb = 0; nb < 4; ++nb)
            attn_out[(i * 4 + b) * DM + n * DHD + nb * 16 + lr16] = f2bf(O[nb][reg] * inv);
    }
}

extern "C" void kernel_launch(void* const* d_in, const int* in_sizes, int n_in,
                              void* d_out, int out_size, void* d_ws, size_t ws_size,
                              hipStream_t stream) {
    const float* w       = (const float*)d_in[0];
    const float* r       = (const float*)d_in[1];
    const float* rwb     = (const float*)d_in[2];
    const float* rrb     = (const float*)d_in[3];
    const float* mems    = (const float*)d_in[4];
    const float* gamma_q = (const float*)d_in[5];
    const float* beta_q  = (const float*)d_in[6];
    const float* gamma_kv= (const float*)d_in[7];
    const float* beta_kv = (const float*)d_in[8];
    const float* Wq      = (const float*)d_in[9];
    const float* Wiq     = (const float*)d_in[10];
    const float* Wk      = (const float*)d_in[11];
    const float* Wv      = (const float*)d_in[12];
    const float* Wr      = (const float*)d_in[13];
    const float* Wintra  = (const float*)d_in[14];
    const float* Winter  = (const float*)d_in[15];
    float* out = (float*)d_out;
    float* ws = (float*)d_ws;

    float* corr = ws;                          // 16,384 f32

    ushort* w_norm_bf  = (ushort*)(corr + 16384);
    ushort* kv_norm_bf = w_norm_bf + 2097152;
    ushort* head_q_bf  = kv_norm_bf + 4194304;   // includes r_w_bias
    ushort* head_k_bf  = head_q_bf + 2097152;
    ushort* head_v_bf  = head_k_bf + 4194304;    // contiguous after head_k
    ushort* head_vT_bf = head_v_bf + 4194304;
    ushort* r_hk_bf    = head_vT_bf + 4194304;
    ushort* attn_o_bf  = r_hk_bf + 1048576;
    ushort* r_bf       = attn_o_bf + 2097152;
    ushort* Wk_bf      = r_bf + 1048576;
    ushort* Wv_bf      = Wk_bf + 1048576;        // contiguous after Wk
    ushort* Wr_bf      = Wv_bf + 1048576;
    ushort* Wq_aug     = Wr_bf + 262144;         // [4][256][1024]
    ushort* Wo_aug     = Wq_aug + 1048576;       // [4][256][1024]

    group_ln_kernel<<<dim3(Q_LEN * BSZ * NG), 64, 0, stream>>>(w, gamma_q, beta_q, w_norm_bf);
    kv_ln_kernel<<<dim3(KL * BSZ), 256, 0, stream>>>(mems, w, gamma_kv, beta_kv, kv_norm_bf);

    cast4_kernel<<<dim3(3328), 256, 0, stream>>>(
        r, Wk, Wv, Wr, r_bf, Wk_bf, Wv_bf, Wr_bf);
    augment_kernel<<<dim3(2048), 256, 0, stream>>>(
        Wq, Wiq, Wq_aug, Wintra, Winter, Wo_aug);

    // head_k & head_v in ONE 128-tile dispatch (z over {Wk,Wv})
    gemm128_bf16_nt<<<dim3(8, 32, 2), 256, 0, stream>>>(
        kv_norm_bf, DM, Wk_bf, 1048576, DM, head_k_bf, 4194304, DM, DM);
    transpose_v_kernel<<<dim3(16, 64), 256, 0, stream>>>(head_v_bf, head_vT_bf);

    // head_q = w_norm x Wq_aug^T (+rwb), z = group, K = 1024
    gemm_bf16_nt<<<dim3(4, 32, 4), 256, 0, stream>>>(
        w_norm_bf, 0, DM, Wq_aug, 262144, DM, nullptr, head_q_bf, DGRP, DM,
        Q_LEN * BSZ, DGRP, DM, nullptr, 0, 0, rwb, DGRP, 0);
    // r_head_k -> bf16 (grouped, K = 256)
    gemm_bf16_nt<<<dim3(4, 16, 4), 256, 0, stream>>>(
        r_bf, DGRP, DM, Wr_bf, DGRP * DGRP, DGRP, nullptr, r_hk_bf, DGRP, DM,
        RL, DGRP, DGRP, nullptr, 0, 0, nullptr, 0, 0);

    corr_kernel<<<dim3(RL / 4, NH), 256, 0, stream>>>(r_hk_bf, rwb, rrb, corr);

    attn_mfma_kernel<<<dim3(Q_LEN / 64, BSZ * NH), 256, 0, stream>>>(
        head_q_bf, head_k_bf, head_vT_bf, r_hk_bf, corr, attn_o_bf);

    // out = attn_o x Wo_aug^T + w (residual), z = group, K = 1024
    gemm_bf16_nt<<<dim3(4, 32, 4), 256, 0, stream>>>(
        attn_o_bf, 0, DM, Wo_aug, 262144, DM, out, nullptr, DGRP, DM,
        Q_LEN * BSZ, DGRP, DM, w, DGRP, DM, nullptr, 0, 0);
}